// Round 7
// baseline (685.909 us; speedup 1.0000x reference)
//
#include <hip/hip_runtime.h>
#include <hip/hip_bf16.h>

// ---- types ----
typedef __bf16 bf16x8 __attribute__((ext_vector_type(8), may_alias));
typedef float f32x4 __attribute__((ext_vector_type(4), may_alias));
typedef unsigned short ushort_a __attribute__((may_alias));

#define MFMA(a, b, c) __builtin_amdgcn_mfma_f32_16x16x32_bf16(a, b, c, 0, 0, 0)

__device__ __forceinline__ unsigned short f2bf(float f) {
  return __builtin_bit_cast(unsigned short, (__bf16)f);
}

// ws element layout (ushort):
//   wfB  [2304][384] @ 0         (884736)
//   wgB  [16][384]   @ 884736    (6144, rows 12..15 zero)
//   waoB [384][384]  @ 890880    (147456)
//   wfoB [384][1536] @ 1038336   (589824)

__global__ __launch_bounds__(256) void prep_weights(
    const float* __restrict__ wf, const float* __restrict__ wg,
    const float* __restrict__ wao, const float* __restrict__ wfo,
    unsigned short* __restrict__ ws) {
  int i = blockIdx.x * 256 + threadIdx.x;
  if (i < 884736) { ws[i] = f2bf(wf[i]); return; }
  int j = i - 884736;
  if (j < 6144) { ws[i] = f2bf(j < 4608 ? wg[j] : 0.0f); return; }
  j -= 6144;
  if (j < 147456) { ws[i] = f2bf(wao[j]); return; }
  j -= 147456;
  if (j < 589824) ws[i] = f2bf(wfo[j]);
}

// 12 waves / block (3 waves per SIMD). LDS layout (bytes), 147456 total:
//   As   [64][384] bf16 row-swz        @ 0       (49152)
//   pair regions (6 x 12288)           @ 49152   (73728)
//       QK [64 rows][128B: Q|K] swz, P overlays; KTb [32][64] @ +8192
//   F tiles (FF) alias pair rgns:      fb{0,1} = 49152 + u*24576  ([64][192])
//   Stg  [64][192] bf16 row-swz        @ 122880  (24576)

__global__ __launch_bounds__(768, 3) void fused_main(
    const float* __restrict__ x,
    const float* __restrict__ bgate,
    const float* __restrict__ srs,
    const float* __restrict__ srb,
    const unsigned short* __restrict__ wsb,
    float* __restrict__ out) {
  const unsigned short* wfB  = wsb;
  const unsigned short* wgB  = wsb + 884736;
  const unsigned short* waoB = wsb + 890880;
  const unsigned short* wfoB = wsb + 1038336;

  __shared__ __align__(16) char smem[147456];
  char* As  = smem;
  char* Stg = smem + 122880;

  const int tid = threadIdx.x;
  const int lane = tid & 63, wave = tid >> 6;       // wave 0..11
  const int l15 = lane & 15, l4 = lane >> 4;
  const int pair = wave >> 1, nb = (wave & 1) * 32; // 6 pairs, own 32 rows
  char* PB  = smem + 49152 + pair * 12288;  // QK rows, later P
  char* KTb = PB + 8192;                    // [32 d][64 m]

  // XCD swizzle: consecutive windows (sharing x/out cache lines) on one XCD
  const int g  = blockIdx.x;
  const int wi = (g & 7) * 128 + (g >> 3);
  const int b = wi >> 6, ghi = (wi >> 3) & 7, gwi = wi & 7;
  const int h0 = ghi * 8, w0 = gwi * 8;

  // ---- gather window -> LDS bf16 [64 tok][384 ch], XOR row-swizzled ----
  {
    const float* xb = x + (size_t)b * 1572864 + h0 * 64 + w0;
    for (int it = 0; it < 4; ++it) {
      int idx = it * 768 + tid;           // [0, 3072): (c, p1) pairs
      int c = idx % 384, p1 = idx / 384;
      const float* src = xb + (size_t)c * 4096 + p1 * 64;
      float4 v0 = *(const float4*)src;
      float4 v1 = *(const float4*)(src + 4);
      float f[8] = {v0.x, v0.y, v0.z, v0.w, v1.x, v1.y, v1.z, v1.w};
#pragma unroll
      for (int jj = 0; jj < 8; ++jj) {
        int row = p1 * 8 + jj;            // token
        int byte = (row * 768 + c * 2) ^ ((row & 7) << 4);
        *(ushort_a*)(As + byte) = f2bf(f[jj]);
      }
    }
  }
  const float ss = srs[0], sbi = srb[0];
  __syncthreads();

  auto ldA = [&](int row, int ks) -> bf16x8 {
    int byte = (row * 768 + ks * 64 + l4 * 16) ^ ((row & 7) << 4);
    return *(const bf16x8*)(As + byte);
  };

  // ---- gate GEMM over own 32 rows: G[n][h] ----
  f32x4 gfr[2] = {};
  {
    const unsigned short* wg0 = wgB + (size_t)l15 * 384 + l4 * 8;
#pragma unroll 2
    for (int ks = 0; ks < 12; ++ks) {
      bf16x8 bg = *(const bf16x8*)(wg0 + ks * 32);
      bf16x8 a0 = ldA(nb + l15, ks), a1 = ldA(nb + 16 + l15, ks);
      gfr[0] = MFMA(a0, bg, gfr[0]);
      gfr[1] = MFMA(a1, bg, gfr[1]);
    }
    float gb = (l15 < 12) ? bgate[l15] : 0.0f;
    gfr[0] += gb;
    gfr[1] += gb;
  }

  f32x4 of[4][2] = {};  // all 64 rows, cols wave*32+{0..32}

  // ---- attention: 2 rounds x 6 heads (one head per pair, half rows/wave) ----
#pragma unroll 1
  for (int r = 0; r < 2; ++r) {
    const int h = r * 6 + pair;
    // QKV GEMM for own 32 rows
    f32x4 qf[2][2] = {}, kf[2][2] = {};
    const unsigned short* wq = wfB + ((size_t)(h * 32) + l15) * 384 + l4 * 8;
    const unsigned short* wk = wq + (size_t)384 * 384;
#pragma unroll 2
    for (int ks = 0; ks < 12; ++ks) {
      bf16x8 a0 = ldA(nb + l15, ks), a1 = ldA(nb + 16 + l15, ks);
#pragma unroll
      for (int nt = 0; nt < 2; ++nt) {
        bf16x8 bq = *(const bf16x8*)(wq + (size_t)nt * 16 * 384 + ks * 32);
        bf16x8 bk = *(const bf16x8*)(wk + (size_t)nt * 16 * 384 + ks * 32);
        qf[0][nt] = MFMA(a0, bq, qf[0][nt]);
        qf[1][nt] = MFMA(a1, bq, qf[1][nt]);
        kf[0][nt] = MFMA(a0, bk, kf[0][nt]);
        kf[1][nt] = MFMA(a1, bk, kf[1][nt]);
      }
    }
    // write QK interleaved row [Q(64B)|K(64B)] + KT (own rows / own m-half)
#pragma unroll
    for (int mt = 0; mt < 2; ++mt)
#pragma unroll
      for (int nt = 0; nt < 2; ++nt)
#pragma unroll
        for (int rr = 0; rr < 4; ++rr) {
          int n = nb + mt * 16 + l4 * 4 + rr;
          int d = nt * 16 + l15;
          int sw = (n & 7) << 4;
          *(ushort_a*)(PB + ((n * 128 + d * 2) ^ sw)) =
              f2bf(qf[mt][nt][rr] * 0.176776695f);
          unsigned short kvv = f2bf(kf[mt][nt][rr]);
          *(ushort_a*)(PB + ((n * 128 + 64 + d * 2) ^ sw)) = kvv;
          *(ushort_a*)(KTb + ((d * 128 + n * 2) ^ ((d & 7) << 4))) = kvv;
        }
    __syncthreads();  // B1: QK/KT visible within pair
    // scores S[n(own half)][m(all)] (K=32, 1 kstep)
    f32x4 sf[2][4] = {};
    {
      bf16x8 bkv[4];
#pragma unroll
      for (int ni = 0; ni < 4; ++ni) {
        int m = ni * 16 + l15;
        bkv[ni] = *(const bf16x8*)(PB + ((m * 128 + 64 + l4 * 16) ^ ((m & 7) << 4)));
      }
#pragma unroll
      for (int mt = 0; mt < 2; ++mt) {
        int n = nb + mt * 16 + l15;
        bf16x8 aq = *(const bf16x8*)(PB + ((n * 128 + l4 * 16) ^ ((n & 7) << 4)));
#pragma unroll
        for (int ni = 0; ni < 4; ++ni) sf[mt][ni] = MFMA(aq, bkv[ni], sf[mt][ni]);
      }
    }
    __syncthreads();  // B2: score reads done before P overlays QK
    // softmax over m; write P (overlays QK region, own rows)
#pragma unroll
    for (int mt = 0; mt < 2; ++mt) {
#pragma unroll
      for (int rr = 0; rr < 4; ++rr) {
        float v0 = sf[mt][0][rr], v1 = sf[mt][1][rr],
              v2 = sf[mt][2][rr], v3 = sf[mt][3][rr];
        float mx = fmaxf(fmaxf(v0, v1), fmaxf(v2, v3));
        mx = fmaxf(mx, __shfl_xor(mx, 1, 64));
        mx = fmaxf(mx, __shfl_xor(mx, 2, 64));
        mx = fmaxf(mx, __shfl_xor(mx, 4, 64));
        mx = fmaxf(mx, __shfl_xor(mx, 8, 64));
        float e0 = __expf(v0 - mx), e1 = __expf(v1 - mx),
              e2 = __expf(v2 - mx), e3 = __expf(v3 - mx);
        float sm = e0 + e1 + e2 + e3;
        sm += __shfl_xor(sm, 1, 64);
        sm += __shfl_xor(sm, 2, 64);
        sm += __shfl_xor(sm, 4, 64);
        sm += __shfl_xor(sm, 8, 64);
        float rs = 1.0f / sm;
        int n = nb + mt * 16 + l4 * 4 + rr;
        int base = n * 128, sw = (n & 7) << 4;
        *(ushort_a*)(PB + ((base + l15 * 2) ^ sw))      = f2bf(e0 * rs);
        *(ushort_a*)(PB + ((base + 32 + l15 * 2) ^ sw)) = f2bf(e1 * rs);
        *(ushort_a*)(PB + ((base + 64 + l15 * 2) ^ sw)) = f2bf(e2 * rs);
        *(ushort_a*)(PB + ((base + 96 + l15 * 2) ^ sw)) = f2bf(e3 * rs);
      }
    }
    // PV: X[n(own half)][d] = P·kv (own P rows + shared KTb)
    f32x4 xo[2][2] = {};
#pragma unroll
    for (int ks = 0; ks < 2; ++ks) {
      bf16x8 bv[2];
#pragma unroll
      for (int nt = 0; nt < 2; ++nt) {
        int d = nt * 16 + l15;
        bv[nt] = *(const bf16x8*)(KTb + ((d * 128 + ks * 64 + l4 * 16) ^ ((d & 7) << 4)));
      }
#pragma unroll
      for (int mt = 0; mt < 2; ++mt) {
        int n = nb + mt * 16 + l15;
        bf16x8 ap = *(const bf16x8*)(PB + ((n * 128 + ks * 64 + l4 * 16) ^ ((n & 7) << 4)));
        xo[mt][0] = MFMA(ap, bv[0], xo[mt][0]);
        xo[mt][1] = MFMA(ap, bv[1], xo[mt][1]);
      }
    }
    // gate + write gated x_attn chunk into Stg [64][192] (6 heads/round)
#pragma unroll
    for (int mt = 0; mt < 2; ++mt) {
#pragma unroll
      for (int rr = 0; rr < 4; ++rr) {
        float gv = __shfl(gfr[mt][rr], (lane & 48) | h, 64);
        float sg = 1.0f / (1.0f + __expf(-gv));
        int n = nb + mt * 16 + l4 * 4 + rr;
        int sw = (n & 7) << 4;
        int c0 = pair * 32 + l15;
        *(ushort_a*)(Stg + ((n * 384 + c0 * 2) ^ sw))        = f2bf(xo[mt][0][rr] * sg);
        *(ushort_a*)(Stg + ((n * 384 + (c0 + 16) * 2) ^ sw)) = f2bf(xo[mt][1][rr] * sg);
      }
    }
    __syncthreads();  // B3: Stg visible
    // attn-out accumulate: of += Stg(64x192) · wao[:, r*192 : r*192+192]^T
    {
      const unsigned short* wao0 =
          waoB + (size_t)(wave * 32 + l15) * 384 + r * 192 + l4 * 8;
#pragma unroll
      for (int ks = 0; ks < 6; ++ks) {
        int kb = ks * 64 + l4 * 16, sz = (l15 & 7) << 4;
        bf16x8 a0 = *(const bf16x8*)(Stg + ((l15 * 384 + kb) ^ sz));
        bf16x8 a1 = *(const bf16x8*)(Stg + (((16 + l15) * 384 + kb) ^ sz));
        bf16x8 a2 = *(const bf16x8*)(Stg + (((32 + l15) * 384 + kb) ^ sz));
        bf16x8 a3 = *(const bf16x8*)(Stg + (((48 + l15) * 384 + kb) ^ sz));
#pragma unroll
        for (int nt = 0; nt < 2; ++nt) {
          bf16x8 bw = *(const bf16x8*)(wao0 + (size_t)nt * 16 * 384 + ks * 32);
          of[0][nt] = MFMA(a0, bw, of[0][nt]);
          of[1][nt] = MFMA(a1, bw, of[1][nt]);
          of[2][nt] = MFMA(a2, bw, of[2][nt]);
          of[3][nt] = MFMA(a3, bw, of[3][nt]);
        }
      }
    }
    // next round's PB writes ordered by B3 + next B1; Stg rewritten after next B2
  }

  // ---- FF: 8 tiles of 192 cols; StarReLU; of += F · wfo^T (1 barrier/tile,
  //      fb double-buffered so consume(t) overlaps produce(t+1)) ----
#pragma unroll 1
  for (int t = 0; t < 8; ++t) {
    f32x4 ffr[4] = {};
    const unsigned short* wfin =
        wfB + (size_t)(768 + t * 192 + wave * 16 + l15) * 384 + l4 * 8;
#pragma unroll 2
    for (int ks = 0; ks < 12; ++ks) {
      bf16x8 a0 = ldA(l15, ks), a1 = ldA(16 + l15, ks),
             a2 = ldA(32 + l15, ks), a3 = ldA(48 + l15, ks);
      bf16x8 bw = *(const bf16x8*)(wfin + ks * 32);
      ffr[0] = MFMA(a0, bw, ffr[0]);
      ffr[1] = MFMA(a1, bw, ffr[1]);
      ffr[2] = MFMA(a2, bw, ffr[2]);
      ffr[3] = MFMA(a3, bw, ffr[3]);
    }
    char* fb = smem + 49152 + (t & 1) * 24576;  // [64][192] bf16, row-swz
#pragma unroll
    for (int mt = 0; mt < 4; ++mt)
#pragma unroll
      for (int rr = 0; rr < 4; ++rr) {
        float v = fmaxf(ffr[mt][rr], 0.0f);
        v = ss * v * v + sbi;  // StarReLU
        int n = mt * 16 + l4 * 4 + rr;
        int cw = wave * 16 + l15;
        *(ushort_a*)(fb + ((n * 384 + cw * 2) ^ ((n & 7) << 4))) = f2bf(v);
      }
    __syncthreads();  // fb[t&1] ready; consume(t-1) done ordering for fb reuse
    const unsigned short* wfo2 =
        wfoB + (size_t)(wave * 32 + l15) * 1536 + t * 192 + l4 * 8;
#pragma unroll
    for (int ks = 0; ks < 6; ++ks) {
      int kb = ks * 64 + l4 * 16, sz = (l15 & 7) << 4;
      bf16x8 a0 = *(const bf16x8*)(fb + ((l15 * 384 + kb) ^ sz));
      bf16x8 a1 = *(const bf16x8*)(fb + (((16 + l15) * 384 + kb) ^ sz));
      bf16x8 a2 = *(const bf16x8*)(fb + (((32 + l15) * 384 + kb) ^ sz));
      bf16x8 a3 = *(const bf16x8*)(fb + (((48 + l15) * 384 + kb) ^ sz));
#pragma unroll
      for (int nt = 0; nt < 2; ++nt) {
        bf16x8 bw = *(const bf16x8*)(wfo2 + (size_t)nt * 16 * 1536 + ks * 32);
        of[0][nt] = MFMA(a0, bw, of[0][nt]);
        of[1][nt] = MFMA(a1, bw, of[1][nt]);
        of[2][nt] = MFMA(a2, bw, of[2][nt]);
        of[3][nt] = MFMA(a3, bw, of[3][nt]);
      }
    }
  }

  // ---- epilogue: scatter out (fp32, NCHW), vectorized dwordx4 ----
  float* ob = out + (size_t)b * 1572864 + h0 * 64 + w0;
#pragma unroll
  for (int nt = 0; nt < 2; ++nt) {
    int col = wave * 32 + nt * 16 + l15;
    float* oc = ob + (size_t)col * 4096;
#pragma unroll
    for (int mt = 0; mt < 4; ++mt) {
      int n0 = mt * 16 + l4 * 4;  // 4 consecutive tokens -> 16B store
      *(f32x4*)(oc + (n0 >> 3) * 64 + (n0 & 7)) = of[mt][nt];
    }
  }
}

extern "C" void kernel_launch(void* const* d_in, const int* in_sizes, int n_in,
                              void* d_out, int out_size, void* d_ws, size_t ws_size,
                              hipStream_t stream) {
  const float* x   = (const float*)d_in[0];
  const float* wf  = (const float*)d_in[1];
  const float* wg  = (const float*)d_in[2];
  const float* bg  = (const float*)d_in[3];
  const float* wao = (const float*)d_in[4];
  const float* wfo = (const float*)d_in[5];
  const float* srs = (const float*)d_in[6];
  const float* srb = (const float*)d_in[7];
  unsigned short* ws = (unsigned short*)d_ws;

  prep_weights<<<6360, 256, 0, stream>>>(wf, wg, wao, wfo, ws);
  fused_main<<<1024, 768, 0, stream>>>(x, bg, srs, srb, ws, (float*)d_out);
}

// Round 9
// 537.061 us; speedup vs baseline: 1.2772x; 1.2772x over previous
//
#include <hip/hip_runtime.h>
#include <hip/hip_bf16.h>

// ---- types ----
typedef __bf16 bf16x8 __attribute__((ext_vector_type(8), may_alias));
typedef float f32x4 __attribute__((ext_vector_type(4), may_alias));
typedef unsigned short ushort_a __attribute__((may_alias));
typedef unsigned int uint_a __attribute__((may_alias));
typedef unsigned short us8 __attribute__((ext_vector_type(8), may_alias));

#define MFMA(a, b, c) __builtin_amdgcn_mfma_f32_16x16x32_bf16(a, b, c, 0, 0, 0)

__device__ __forceinline__ unsigned short f2bf(float f) {
  return __builtin_bit_cast(unsigned short, (__bf16)f);
}
__device__ __forceinline__ float bf2f(unsigned short u) {
  unsigned v = ((unsigned)u) << 16;
  return __builtin_bit_cast(float, v);
}

// ws layout (ushort elements):
//   wfB  [2304][384] @ 0
//   wgB  [128][384]  @ 884736    (rows >=12 zero)
//   waoB [384][384]  @ 933888
//   wfoB [384][1536] @ 1081344
//   xg   [65536][384]  @ 1671168   (gathered x, bf16 token-major)
//   fused[65536][2304] @ 26836992  (q | kv | StarReLU(ff)); q overwritten by x_attn
//   gate [65536][16]   @ 177831936
#define OFF_WG 884736
#define OFF_WAO 933888
#define OFF_WFO 1081344
#define OFF_XG 1671168
#define OFF_FUSED 26836992
#define OFF_GATE 177831936
#define WS_NEED 357761024ull

__global__ __launch_bounds__(256) void prep_weights(
    const float* __restrict__ wf, const float* __restrict__ wg,
    const float* __restrict__ wao, const float* __restrict__ wfo,
    unsigned short* __restrict__ ws) {
  int i = blockIdx.x * 256 + threadIdx.x;
  if (i < 884736) { ws[i] = f2bf(wf[i]); return; }
  int j = i - 884736;
  if (j < 49152) { ws[i] = f2bf(j < 4608 ? wg[j] : 0.0f); return; }
  j -= 49152;
  if (j < 147456) { ws[i] = f2bf(wao[j]); return; }
  j -= 147456;
  if (j < 589824) ws[i] = f2bf(wfo[j]);
}

// ---- k0: gather NCHW fp32 -> token-major bf16 xg [65536][384] ----
__global__ __launch_bounds__(256) void k0_gather(const float* __restrict__ x,
                                                 unsigned short* __restrict__ xg) {
  __shared__ __align__(16) char As[49152];
  int tid = threadIdx.x, wi = blockIdx.x;
  int b = wi >> 6, ghi = (wi >> 3) & 7, gwi = wi & 7;
  const float* xb = x + (size_t)b * 1572864 + (ghi * 8) * 64 + gwi * 8;
  for (int it = 0; it < 12; ++it) {
    int idx = it * 256 + tid;  // (c, p1)
    int c = idx % 384, p1 = idx / 384;
    const float* src = xb + (size_t)c * 4096 + p1 * 64;
    float4 v0 = *(const float4*)src, v1 = *(const float4*)(src + 4);
    float f[8] = {v0.x, v0.y, v0.z, v0.w, v1.x, v1.y, v1.z, v1.w};
#pragma unroll
    for (int jj = 0; jj < 8; ++jj) {
      int row = p1 * 8 + jj;
      int byte = (row * 768 + c * 2) ^ ((row & 7) << 4);
      *(ushort_a*)(As + byte) = f2bf(f[jj]);
    }
  }
  __syncthreads();
  unsigned short* og = xg + (size_t)wi * 24576;
#pragma unroll
  for (int it = 0; it < 12; ++it) {
    int idx = it * 256 + tid;
    int row = idx / 48, c = idx % 48;
    int byte = (row * 768 + c * 16) ^ ((row & 7) << 4);
    *(us8*)(og + (size_t)row * 384 + c * 8) = *(us8*)(As + byte);
  }
}

// ---- k1: fused = xg . W_fused^T  (M=65536, N=2304 + gate 16, K=384) ----
// grid 512*19; nb 0..17 -> fused cols nb*128 (StarReLU for nb>=6); nb==18 -> gate
__global__ __launch_bounds__(512, 4) void k1_gemm(unsigned short* __restrict__ ws,
                                                  const float* __restrict__ srs,
                                                  const float* __restrict__ srb) {
  __shared__ __align__(16) char sm[65536];  // A bufs @0/16384, B bufs @32768/49152
  const int tid = threadIdx.x, lane = tid & 63, wave = tid >> 6;
  const int l15 = lane & 15, l4 = lane >> 4;
  const int wr = wave & 3, wc = wave >> 2;
  const int bid = blockIdx.x, mb = bid & 511, nb = bid >> 9;
  const unsigned short* Ab = ws + OFF_XG + (size_t)mb * 128 * 384;
  const unsigned short* Bb =
      (nb < 18) ? ws + (size_t)nb * 128 * 384 : ws + OFF_WG;
  const int srow = tid >> 3, sc = tid & 7;
  f32x4 of[2][4] = {};
  us8 stA[2], stB[2];
#pragma unroll
  for (int r2 = 0; r2 < 2; ++r2) {
    int row = srow + 64 * r2;
    stA[r2] = *(const us8*)(Ab + (size_t)row * 384 + sc * 8);
    stB[r2] = *(const us8*)(Bb + (size_t)row * 384 + sc * 8);
  }
#pragma unroll
  for (int r2 = 0; r2 < 2; ++r2) {
    int row = srow + 64 * r2;
    int byte = (row * 128 + sc * 16) ^ ((row & 7) << 4);
    *(us8*)(sm + byte) = stA[r2];
    *(us8*)(sm + 32768 + byte) = stB[r2];
  }
  __syncthreads();
#pragma unroll 1
  for (int ks = 0; ks < 6; ++ks) {
    int cur = (ks & 1) * 16384;
    if (ks < 5) {
#pragma unroll
      for (int r2 = 0; r2 < 2; ++r2) {
        int row = srow + 64 * r2;
        stA[r2] = *(const us8*)(Ab + (size_t)row * 384 + (ks + 1) * 64 + sc * 8);
        stB[r2] = *(const us8*)(Bb + (size_t)row * 384 + (ks + 1) * 64 + sc * 8);
      }
    }
    // consume BOTH 32-element halves of the staged 64-K chunk (r8 bugfix)
#pragma unroll
    for (int kk = 0; kk < 2; ++kk) {
      bf16x8 af[2], bfr[4];
#pragma unroll
      for (int mt = 0; mt < 2; ++mt) {
        int row = wr * 32 + mt * 16 + l15;
        af[mt] = *(const bf16x8*)(sm + cur +
                                  ((row * 128 + kk * 64 + l4 * 16) ^ ((row & 7) << 4)));
      }
#pragma unroll
      for (int nt = 0; nt < 4; ++nt) {
        int row = wc * 64 + nt * 16 + l15;
        bfr[nt] = *(const bf16x8*)(sm + 32768 + cur +
                                   ((row * 128 + kk * 64 + l4 * 16) ^ ((row & 7) << 4)));
      }
#pragma unroll
      for (int mt = 0; mt < 2; ++mt)
#pragma unroll
        for (int nt = 0; nt < 4; ++nt)
          of[mt][nt] = MFMA(af[mt], bfr[nt], of[mt][nt]);
    }
    if (ks < 5) {
      int nxt = ((ks + 1) & 1) * 16384;
#pragma unroll
      for (int r2 = 0; r2 < 2; ++r2) {
        int row = srow + 64 * r2;
        int byte = (row * 128 + sc * 16) ^ ((row & 7) << 4);
        *(us8*)(sm + nxt + byte) = stA[r2];
        *(us8*)(sm + 32768 + nxt + byte) = stB[r2];
      }
    }
    __syncthreads();
  }
  // epilogue: accs -> LDS bf16 [128][256B] swz -> coalesced global
  const float ssc = srs[0], sbi = srb[0];
  const bool ffreg = (nb >= 6) && (nb < 18);
#pragma unroll
  for (int mt = 0; mt < 2; ++mt)
#pragma unroll
    for (int nt = 0; nt < 4; ++nt)
#pragma unroll
      for (int rr = 0; rr < 4; ++rr) {
        int row = wr * 32 + mt * 16 + l4 * 4 + rr;
        int col = wc * 64 + nt * 16 + l15;
        float v = of[mt][nt][rr];
        if (ffreg) { v = fmaxf(v, 0.0f); v = ssc * v * v + sbi; }
        *(ushort_a*)(sm + ((row * 256 + col * 2) ^ ((row & 7) << 4))) = f2bf(v);
      }
  __syncthreads();
  if (nb < 18) {
    unsigned short* fo = ws + OFF_FUSED + (size_t)mb * 128 * 2304 + nb * 128;
#pragma unroll
    for (int r2 = 0; r2 < 4; ++r2) {
      int idx = r2 * 512 + tid;
      int row = idx >> 4, c = idx & 15;
      int byte = (row * 256 + c * 16) ^ ((row & 7) << 4);
      *(us8*)(fo + (size_t)row * 2304 + c * 8) = *(us8*)(sm + byte);
    }
  } else {
    unsigned short* go = ws + OFF_GATE + (size_t)mb * 128 * 16;
#pragma unroll
    for (int r2 = 0; r2 < 4; ++r2) {
      int idx = r2 * 512 + tid;
      int row = idx >> 4, c = idx & 15;
      if (c < 2) {
        int byte = (row * 256 + c * 16) ^ ((row & 7) << 4);
        *(us8*)(go + (size_t)row * 16 + c * 8) = *(us8*)(sm + byte);
      }
    }
  }
}

// ---- k2: windowed attention (per-wave private, no barriers) ----
// block = 1 window, 4 waves x 3 heads; writes gated x_attn over the q region.
__global__ __launch_bounds__(256, 3) void k2_attn(unsigned short* __restrict__ ws,
                                                  const float* __restrict__ bgate) {
  __shared__ __align__(16) char sm[49152];
  const int tid = threadIdx.x, lane = tid & 63, wave = tid >> 6;
  const int l15 = lane & 15, l4 = lane >> 4;
  char* kvT = sm + wave * 12288;  // [32 d][128B m]
  char* Pb = kvT + 4096;          // [64 n][128B m]
  const int wi = blockIdx.x;
  const size_t T0 = (size_t)wi * 64;
  unsigned short* fused = ws + OFF_FUSED;
  const unsigned short* gb = ws + OFF_GATE;
  const f32x4 zz = {};
#pragma unroll 1
  for (int hi = 0; hi < 3; ++hi) {
    const int h = wave + hi * 4;
    bf16x8 akv[4], bq[4];
#pragma unroll
    for (int t = 0; t < 4; ++t) {
      akv[t] = *(const bf16x8*)(fused + (T0 + t * 16 + l15) * 2304 + 384 + h * 32 + l4 * 8);
      bq[t] = *(const bf16x8*)(fused + (T0 + t * 16 + l15) * 2304 + h * 32 + l4 * 8);
    }
    // S^T[m][n] = sum_d kv[m][d] q[n][d]
    f32x4 sfT[4][4];
#pragma unroll
    for (int mt = 0; mt < 4; ++mt)
#pragma unroll
      for (int ni = 0; ni < 4; ++ni) sfT[mt][ni] = MFMA(akv[mt], bq[ni], zz);
    // kvT build (scalar scatter, per-wave private)
#pragma unroll
    for (int mt = 0; mt < 4; ++mt) {
      us8 u = __builtin_bit_cast(us8, akv[mt]);
      int m = mt * 16 + l15;
#pragma unroll
      for (int j = 0; j < 8; ++j) {
        int d = l4 * 8 + j;
        *(ushort_a*)(kvT + ((d * 128 + m * 2) ^ ((d & 7) << 4))) = u[j];
      }
    }
    // softmax over m (16 in-lane + shfl over lane bits 4,5); write P[n][m]
#pragma unroll
    for (int ni = 0; ni < 4; ++ni) {
      float s[16];
#pragma unroll
      for (int mt = 0; mt < 4; ++mt)
#pragma unroll
        for (int rr = 0; rr < 4; ++rr)
          s[mt * 4 + rr] = sfT[mt][ni][rr] * 0.176776695f;
      float mx = s[0];
#pragma unroll
      for (int q2 = 1; q2 < 16; ++q2) mx = fmaxf(mx, s[q2]);
      mx = fmaxf(mx, __shfl_xor(mx, 16, 64));
      mx = fmaxf(mx, __shfl_xor(mx, 32, 64));
      float sum = 0.0f;
#pragma unroll
      for (int q2 = 0; q2 < 16; ++q2) {
        s[q2] = __expf(s[q2] - mx);
        sum += s[q2];
      }
      sum += __shfl_xor(sum, 16, 64);
      sum += __shfl_xor(sum, 32, 64);
      float rs = 1.0f / sum;
      int n = ni * 16 + l15;
      int rowb = n * 128, sw = (n & 7) << 4;
#pragma unroll
      for (int mt = 0; mt < 4; ++mt) {
        int m = mt * 16 + l4 * 4;
        unsigned p0 = (unsigned)f2bf(s[mt * 4 + 0] * rs) |
                      ((unsigned)f2bf(s[mt * 4 + 1] * rs) << 16);
        unsigned p1 = (unsigned)f2bf(s[mt * 4 + 2] * rs) |
                      ((unsigned)f2bf(s[mt * 4 + 3] * rs) << 16);
        *(uint_a*)(Pb + ((rowb + m * 2) ^ sw)) = p0;
        *(uint_a*)(Pb + ((rowb + (m + 2) * 2) ^ sw)) = p1;
      }
    }
    // PV: X[n][d]
    f32x4 xo[4][2] = {};
#pragma unroll
    for (int ks = 0; ks < 2; ++ks) {
      bf16x8 bv[2];
#pragma unroll
      for (int dt = 0; dt < 2; ++dt) {
        int d = dt * 16 + l15;
        bv[dt] = *(const bf16x8*)(kvT + ((d * 128 + ks * 64 + l4 * 16) ^ ((d & 7) << 4)));
      }
#pragma unroll
      for (int nt = 0; nt < 4; ++nt) {
        int n = nt * 16 + l15;
        bf16x8 ap = *(const bf16x8*)(Pb + ((n * 128 + ks * 64 + l4 * 16) ^ ((n & 7) << 4)));
        xo[nt][0] = MFMA(ap, bv[0], xo[nt][0]);
        xo[nt][1] = MFMA(ap, bv[1], xo[nt][1]);
      }
    }
    // gate + store gated x_attn into q slot
    const float bgh = bgate[h];
#pragma unroll
    for (int nt = 0; nt < 4; ++nt)
#pragma unroll
      for (int rr = 0; rr < 4; ++rr) {
        int n = nt * 16 + l4 * 4 + rr;
        float gv = bf2f(gb[(T0 + n) * 16 + h]) + bgh;
        float sg = 1.0f / (1.0f + __expf(-gv));
#pragma unroll
        for (int dt = 0; dt < 2; ++dt)
          fused[(T0 + n) * 2304 + h * 32 + dt * 16 + l15] =
              f2bf(xo[nt][dt][rr] * sg);
      }
  }
}

// ---- k3: out = Xattn . wao^T + F . wfo^T  (K=1920, NCHW epilogue) ----
__global__ __launch_bounds__(512, 4) void k3_gemm(const unsigned short* __restrict__ ws,
                                                  float* __restrict__ out) {
  __shared__ __align__(16) char sm[65536];
  const int tid = threadIdx.x, lane = tid & 63, wave = tid >> 6;
  const int l15 = lane & 15, l4 = lane >> 4;
  const int wr = wave & 3, wc = wave >> 2;
  const int bid = blockIdx.x, mb = bid & 511, nB = bid >> 9;
  const size_t T0 = (size_t)mb * 128;
  const unsigned short* fA = ws + OFF_FUSED + T0 * 2304;
  const unsigned short* wao = ws + OFF_WAO + (size_t)(nB * 128) * 384;
  const unsigned short* wfo = ws + OFF_WFO + (size_t)(nB * 128) * 1536;
  const int srow = tid >> 3, sc = tid & 7;
  f32x4 of[2][4] = {};
  us8 stA[2], stB[2];
  auto loadAB = [&](int ks) {
    int ac = ks < 6 ? ks * 64 : 768 + (ks - 6) * 64;
#pragma unroll
    for (int r2 = 0; r2 < 2; ++r2) {
      int row = srow + 64 * r2;
      stA[r2] = *(const us8*)(fA + (size_t)row * 2304 + ac + sc * 8);
      if (ks < 6)
        stB[r2] = *(const us8*)(wao + (size_t)row * 384 + ks * 64 + sc * 8);
      else
        stB[r2] = *(const us8*)(wfo + (size_t)row * 1536 + (ks - 6) * 64 + sc * 8);
    }
  };
  auto writeAB = [&](int buf) {
#pragma unroll
    for (int r2 = 0; r2 < 2; ++r2) {
      int row = srow + 64 * r2;
      int byte = (row * 128 + sc * 16) ^ ((row & 7) << 4);
      *(us8*)(sm + buf + byte) = stA[r2];
      *(us8*)(sm + 32768 + buf + byte) = stB[r2];
    }
  };
  loadAB(0);
  writeAB(0);
  __syncthreads();
#pragma unroll 1
  for (int ks = 0; ks < 30; ++ks) {
    int cur = (ks & 1) * 16384;
    if (ks < 29) loadAB(ks + 1);
    // consume BOTH 32-element halves of the staged 64-K chunk (r8 bugfix)
#pragma unroll
    for (int kk = 0; kk < 2; ++kk) {
      bf16x8 af[2], bfr[4];
#pragma unroll
      for (int mt = 0; mt < 2; ++mt) {
        int row = wr * 32 + mt * 16 + l15;
        af[mt] = *(const bf16x8*)(sm + cur +
                                  ((row * 128 + kk * 64 + l4 * 16) ^ ((row & 7) << 4)));
      }
#pragma unroll
      for (int nt = 0; nt < 4; ++nt) {
        int row = wc * 64 + nt * 16 + l15;
        bfr[nt] = *(const bf16x8*)(sm + 32768 + cur +
                                   ((row * 128 + kk * 64 + l4 * 16) ^ ((row & 7) << 4)));
      }
#pragma unroll
      for (int mt = 0; mt < 2; ++mt)
#pragma unroll
        for (int nt = 0; nt < 4; ++nt)
          of[mt][nt] = MFMA(af[mt], bfr[nt], of[mt][nt]);
    }
    if (ks < 29) writeAB(((ks + 1) & 1) * 16384);
    __syncthreads();
  }
  // epilogue: NCHW fp32 scatter
#pragma unroll
  for (int mt = 0; mt < 2; ++mt) {
    int n0 = wr * 32 + mt * 16 + l4 * 4;
    int T = (int)T0 + n0;
    int wi = T >> 6, n = T & 63;
    int b = wi >> 6, ghi = (wi >> 3) & 7, gwi = wi & 7;
    float* ob = out + (size_t)b * 1572864 + (size_t)(ghi * 8 + (n >> 3)) * 64 +
                gwi * 8 + (n & 7);
#pragma unroll
    for (int nt = 0; nt < 4; ++nt) {
      int c = nB * 128 + wc * 64 + nt * 16 + l15;
      *(f32x4*)(ob + (size_t)c * 4096) = of[mt][nt];
    }
  }
}

// ---- fallback: round-6 fused kernel (weight offsets updated) ----
__global__ __launch_bounds__(512, 2) void fused_fallback(
    const float* __restrict__ x, const float* __restrict__ bgate,
    const float* __restrict__ srs, const float* __restrict__ srb,
    const unsigned short* __restrict__ wsb, float* __restrict__ out) {
  const unsigned short* wfB = wsb;
  const unsigned short* wgB = wsb + OFF_WG;
  const unsigned short* waoB = wsb + OFF_WAO;
  const unsigned short* wfoB = wsb + OFF_WFO;
  __shared__ __align__(16) char smem[114688];
  char* As = smem;
  char* Stg = smem + 98304;
  const int tid = threadIdx.x;
  const int lane = tid & 63, wave = tid >> 6;
  const int l15 = lane & 15, l4 = lane >> 4;
  const int pair = wave >> 1, nb = (wave & 1) * 32;
  char* PB = smem + 49152 + pair * 12288;
  char* KTb = PB + 8192;
  const int g = blockIdx.x;
  const int wi = (g & 7) * 128 + (g >> 3);
  const int b = wi >> 6, ghi = (wi >> 3) & 7, gwi = wi & 7;
  const int h0 = ghi * 8, w0 = gwi * 8;
  {
    const float* xb = x + (size_t)b * 1572864 + h0 * 64 + w0;
    for (int it = 0; it < 6; ++it) {
      int idx = it * 512 + tid;
      int c = idx % 384, p1 = idx / 384;
      const float* src = xb + (size_t)c * 4096 + p1 * 64;
      float4 v0 = *(const float4*)src;
      float4 v1 = *(const float4*)(src + 4);
      float f[8] = {v0.x, v0.y, v0.z, v0.w, v1.x, v1.y, v1.z, v1.w};
#pragma unroll
      for (int jj = 0; jj < 8; ++jj) {
        int row = p1 * 8 + jj;
        int byte = (row * 768 + c * 2) ^ ((row & 7) << 4);
        *(ushort_a*)(As + byte) = f2bf(f[jj]);
      }
    }
  }
  const float ss = srs[0], sbi = srb[0];
  __syncthreads();
  auto ldA = [&](int row, int ks) -> bf16x8 {
    int byte = (row * 768 + ks * 64 + l4 * 16) ^ ((row & 7) << 4);
    return *(const bf16x8*)(As + byte);
  };
  f32x4 gfr[2] = {};
  {
    const unsigned short* wg0 = wgB + (size_t)l15 * 384 + l4 * 8;
#pragma unroll 2
    for (int ks = 0; ks < 12; ++ks) {
      bf16x8 bg = *(const bf16x8*)(wg0 + ks * 32);
      bf16x8 a0 = ldA(nb + l15, ks), a1 = ldA(nb + 16 + l15, ks);
      gfr[0] = MFMA(a0, bg, gfr[0]);
      gfr[1] = MFMA(a1, bg, gfr[1]);
    }
    float gb = (l15 < 12) ? bgate[l15] : 0.0f;
    gfr[0] += gb;
    gfr[1] += gb;
  }
  f32x4 of[4][3] = {};
#pragma unroll 1
  for (int r = 0; r < 3; ++r) {
    const int h = r * 4 + pair;
    f32x4 qf[2][2] = {}, kf[2][2] = {};
    const unsigned short* wq = wfB + ((size_t)(h * 32) + l15) * 384 + l4 * 8;
    const unsigned short* wk = wq + (size_t)384 * 384;
#pragma unroll 2
    for (int ks = 0; ks < 12; ++ks) {
      bf16x8 a0 = ldA(nb + l15, ks), a1 = ldA(nb + 16 + l15, ks);
#pragma unroll
      for (int nt = 0; nt < 2; ++nt) {
        bf16x8 bq = *(const bf16x8*)(wq + (size_t)nt * 16 * 384 + ks * 32);
        bf16x8 bk = *(const bf16x8*)(wk + (size_t)nt * 16 * 384 + ks * 32);
        qf[0][nt] = MFMA(a0, bq, qf[0][nt]);
        qf[1][nt] = MFMA(a1, bq, qf[1][nt]);
        kf[0][nt] = MFMA(a0, bk, kf[0][nt]);
        kf[1][nt] = MFMA(a1, bk, kf[1][nt]);
      }
    }
#pragma unroll
    for (int mt = 0; mt < 2; ++mt)
#pragma unroll
      for (int nt = 0; nt < 2; ++nt)
#pragma unroll
        for (int rr = 0; rr < 4; ++rr) {
          int n = nb + mt * 16 + l4 * 4 + rr;
          int d = nt * 16 + l15;
          int sw = (n & 7) << 4;
          *(ushort_a*)(PB + ((n * 128 + d * 2) ^ sw)) =
              f2bf(qf[mt][nt][rr] * 0.176776695f);
          unsigned short kvv = f2bf(kf[mt][nt][rr]);
          *(ushort_a*)(PB + ((n * 128 + 64 + d * 2) ^ sw)) = kvv;
          *(ushort_a*)(KTb + ((d * 128 + n * 2) ^ ((d & 7) << 4))) = kvv;
        }
    __syncthreads();
    f32x4 sf[2][4] = {};
    {
      bf16x8 bkv[4];
#pragma unroll
      for (int ni = 0; ni < 4; ++ni) {
        int m = ni * 16 + l15;
        bkv[ni] = *(const bf16x8*)(PB + ((m * 128 + 64 + l4 * 16) ^ ((m & 7) << 4)));
      }
#pragma unroll
      for (int mt = 0; mt < 2; ++mt) {
        int n = nb + mt * 16 + l15;
        bf16x8 aq = *(const bf16x8*)(PB + ((n * 128 + l4 * 16) ^ ((n & 7) << 4)));
#pragma unroll
        for (int ni = 0; ni < 4; ++ni) sf[mt][ni] = MFMA(aq, bkv[ni], sf[mt][ni]);
      }
    }
    __syncthreads();
#pragma unroll
    for (int mt = 0; mt < 2; ++mt) {
#pragma unroll
      for (int rr = 0; rr < 4; ++rr) {
        float v0 = sf[mt][0][rr], v1 = sf[mt][1][rr], v2 = sf[mt][2][rr],
              v3 = sf[mt][3][rr];
        float mx = fmaxf(fmaxf(v0, v1), fmaxf(v2, v3));
        mx = fmaxf(mx, __shfl_xor(mx, 1, 64));
        mx = fmaxf(mx, __shfl_xor(mx, 2, 64));
        mx = fmaxf(mx, __shfl_xor(mx, 4, 64));
        mx = fmaxf(mx, __shfl_xor(mx, 8, 64));
        float e0 = __expf(v0 - mx), e1 = __expf(v1 - mx), e2 = __expf(v2 - mx),
              e3 = __expf(v3 - mx);
        float sm2 = e0 + e1 + e2 + e3;
        sm2 += __shfl_xor(sm2, 1, 64);
        sm2 += __shfl_xor(sm2, 2, 64);
        sm2 += __shfl_xor(sm2, 4, 64);
        sm2 += __shfl_xor(sm2, 8, 64);
        float rs = 1.0f / sm2;
        int n = nb + mt * 16 + l4 * 4 + rr;
        int base = n * 128, sw = (n & 7) << 4;
        *(ushort_a*)(PB + ((base + l15 * 2) ^ sw)) = f2bf(e0 * rs);
        *(ushort_a*)(PB + ((base + 32 + l15 * 2) ^ sw)) = f2bf(e1 * rs);
        *(ushort_a*)(PB + ((base + 64 + l15 * 2) ^ sw)) = f2bf(e2 * rs);
        *(ushort_a*)(PB + ((base + 96 + l15 * 2) ^ sw)) = f2bf(e3 * rs);
      }
    }
    f32x4 xo[2][2] = {};
#pragma unroll
    for (int ks = 0; ks < 2; ++ks) {
      bf16x8 bv[2];
#pragma unroll
      for (int nt = 0; nt < 2; ++nt) {
        int d = nt * 16 + l15;
        bv[nt] = *(const bf16x8*)(KTb + ((d * 128 + ks * 64 + l4 * 16) ^ ((d & 7) << 4)));
      }
#pragma unroll
      for (int mt = 0; mt < 2; ++mt) {
        int n = nb + mt * 16 + l15;
        bf16x8 ap = *(const bf16x8*)(PB + ((n * 128 + ks * 64 + l4 * 16) ^ ((n & 7) << 4)));
        xo[mt][0] = MFMA(ap, bv[0], xo[mt][0]);
        xo[mt][1] = MFMA(ap, bv[1], xo[mt][1]);
      }
    }
#pragma unroll
    for (int mt = 0; mt < 2; ++mt) {
#pragma unroll
      for (int rr = 0; rr < 4; ++rr) {
        float gv = __shfl(gfr[mt][rr], (lane & 48) | h, 64);
        float sg = 1.0f / (1.0f + __expf(-gv));
        int n = nb + mt * 16 + l4 * 4 + rr;
        int sw = (n & 7) << 4;
        int c0 = pair * 32 + l15;
        *(ushort_a*)(Stg + ((n * 256 + c0 * 2) ^ sw)) = f2bf(xo[mt][0][rr] * sg);
        *(ushort_a*)(Stg + ((n * 256 + (c0 + 16) * 2) ^ sw)) = f2bf(xo[mt][1][rr] * sg);
      }
    }
    __syncthreads();
    {
      const unsigned short* wao0 =
          waoB + (size_t)(wave * 48 + l15) * 384 + r * 128 + l4 * 8;
#pragma unroll
      for (int ks = 0; ks < 4; ++ks) {
        int kb = ks * 64 + l4 * 16, sz = (l15 & 7) << 4;
        bf16x8 a0 = *(const bf16x8*)(Stg + ((l15 * 256 + kb) ^ sz));
        bf16x8 a1 = *(const bf16x8*)(Stg + (((16 + l15) * 256 + kb) ^ sz));
        bf16x8 a2 = *(const bf16x8*)(Stg + (((32 + l15) * 256 + kb) ^ sz));
        bf16x8 a3 = *(const bf16x8*)(Stg + (((48 + l15) * 256 + kb) ^ sz));
#pragma unroll
        for (int nt = 0; nt < 3; ++nt) {
          bf16x8 bw = *(const bf16x8*)(wao0 + (size_t)nt * 16 * 384 + ks * 32);
          of[0][nt] = MFMA(a0, bw, of[0][nt]);
          of[1][nt] = MFMA(a1, bw, of[1][nt]);
          of[2][nt] = MFMA(a2, bw, of[2][nt]);
          of[3][nt] = MFMA(a3, bw, of[3][nt]);
        }
      }
    }
  }
#pragma unroll 1
  for (int tg = 0; tg < 6; ++tg) {
    f32x4 ffr[4][2] = {};
    const unsigned short* wfin0 =
        wfB + (size_t)(768 + tg * 256 + wave * 16 + l15) * 384 + l4 * 8;
    const unsigned short* wfin1 = wfin0 + (size_t)128 * 384;
#pragma unroll 2
    for (int ks = 0; ks < 12; ++ks) {
      bf16x8 a0 = ldA(l15, ks), a1 = ldA(16 + l15, ks), a2 = ldA(32 + l15, ks),
             a3 = ldA(48 + l15, ks);
      bf16x8 bw0 = *(const bf16x8*)(wfin0 + ks * 32);
      ffr[0][0] = MFMA(a0, bw0, ffr[0][0]);
      ffr[1][0] = MFMA(a1, bw0, ffr[1][0]);
      ffr[2][0] = MFMA(a2, bw0, ffr[2][0]);
      ffr[3][0] = MFMA(a3, bw0, ffr[3][0]);
      bf16x8 bw1 = *(const bf16x8*)(wfin1 + ks * 32);
      ffr[0][1] = MFMA(a0, bw1, ffr[0][1]);
      ffr[1][1] = MFMA(a1, bw1, ffr[1][1]);
      ffr[2][1] = MFMA(a2, bw1, ffr[2][1]);
      ffr[3][1] = MFMA(a3, bw1, ffr[3][1]);
    }
#pragma unroll
    for (int u = 0; u < 2; ++u) {
      char* fb = smem + 49152 + u * 16384;
#pragma unroll
      for (int mt = 0; mt < 4; ++mt)
#pragma unroll
        for (int rr = 0; rr < 4; ++rr) {
          float v = fmaxf(ffr[mt][u][rr], 0.0f);
          v = ss * v * v + sbi;
          int n = mt * 16 + l4 * 4 + rr;
          int cw = wave * 16 + l15;
          *(ushort_a*)(fb + ((n * 256 + cw * 2) ^ ((n & 7) << 4))) = f2bf(v);
        }
    }
    __syncthreads();
#pragma unroll 1
    for (int u = 0; u < 2; ++u) {
      char* fb = smem + 49152 + u * 16384;
      const unsigned short* wfo2 =
          wfoB + (size_t)(wave * 48 + l15) * 1536 + (tg * 2 + u) * 128 + l4 * 8;
#pragma unroll
      for (int ks = 0; ks < 4; ++ks) {
        int kb = ks * 64 + l4 * 16, sz = (l15 & 7) << 4;
        bf16x8 a0 = *(const bf16x8*)(fb + ((l15 * 256 + kb) ^ sz));
        bf16x8 a1 = *(const bf16x8*)(fb + (((16 + l15) * 256 + kb) ^ sz));
        bf16x8 a2 = *(const bf16x8*)(fb + (((32 + l15) * 256 + kb) ^ sz));
        bf16x8 a3 = *(const bf16x8*)(fb + (((48 + l15) * 256 + kb) ^ sz));
#pragma unroll
        for (int nt = 0; nt < 3; ++nt) {
          bf16x8 bw = *(const bf16x8*)(wfo2 + (size_t)nt * 16 * 1536 + ks * 32);
          of[0][nt] = MFMA(a0, bw, of[0][nt]);
          of[1][nt] = MFMA(a1, bw, of[1][nt]);
          of[2][nt] = MFMA(a2, bw, of[2][nt]);
          of[3][nt] = MFMA(a3, bw, of[3][nt]);
        }
      }
    }
    __syncthreads();
  }
  float* ob = out + (size_t)b * 1572864 + h0 * 64 + w0;
#pragma unroll
  for (int nt = 0; nt < 3; ++nt) {
    int col = wave * 48 + nt * 16 + l15;
    float* oc = ob + (size_t)col * 4096;
#pragma unroll
    for (int mt = 0; mt < 4; ++mt) {
      int n0 = mt * 16 + l4 * 4;
      *(f32x4*)(oc + (n0 >> 3) * 64 + (n0 & 7)) = of[mt][nt];
    }
  }
}

extern "C" void kernel_launch(void* const* d_in, const int* in_sizes, int n_in,
                              void* d_out, int out_size, void* d_ws, size_t ws_size,
                              hipStream_t stream) {
  const float* x = (const float*)d_in[0];
  const float* wf = (const float*)d_in[1];
  const float* wg = (const float*)d_in[2];
  const float* bg = (const float*)d_in[3];
  const float* wao = (const float*)d_in[4];
  const float* wfo = (const float*)d_in[5];
  const float* srs = (const float*)d_in[6];
  const float* srb = (const float*)d_in[7];
  unsigned short* ws = (unsigned short*)d_ws;

  prep_weights<<<6528, 256, 0, stream>>>(wf, wg, wao, wfo, ws);
  if (ws_size >= WS_NEED) {
    k0_gather<<<1024, 256, 0, stream>>>(x, ws + OFF_XG);
    k1_gemm<<<512 * 19, 512, 0, stream>>>(ws, srs, srb);
    k2_attn<<<1024, 256, 0, stream>>>(ws, bg);
    k3_gemm<<<512 * 3, 512, 0, stream>>>(ws, (float*)d_out);
  } else {
    fused_fallback<<<1024, 512, 0, stream>>>(x, bg, srs, srb, ws, (float*)d_out);
  }
}

// Round 10
// 499.494 us; speedup vs baseline: 1.3732x; 1.0752x over previous
//
#include <hip/hip_runtime.h>
#include <hip/hip_bf16.h>

// ---- types ----
typedef __bf16 bf16x8 __attribute__((ext_vector_type(8), may_alias));
typedef float f32x4 __attribute__((ext_vector_type(4), may_alias));
typedef unsigned short ushort_a __attribute__((may_alias));
typedef unsigned int uint_a __attribute__((may_alias));
typedef unsigned short us8 __attribute__((ext_vector_type(8), may_alias));

#define MFMA(a, b, c) __builtin_amdgcn_mfma_f32_16x16x32_bf16(a, b, c, 0, 0, 0)

__device__ __forceinline__ unsigned short f2bf(float f) {
  return __builtin_bit_cast(unsigned short, (__bf16)f);
}
__device__ __forceinline__ float bf2f(unsigned short u) {
  unsigned v = ((unsigned)u) << 16;
  return __builtin_bit_cast(float, v);
}

// ws layout (ushort elements):
//   wfB  [2304][384] @ 0
//   wgB  [128][384]  @ 884736    (rows >=12 zero)
//   waoB [384][384]  @ 933888
//   wfoB [384][1536] @ 1081344
//   xg   [65536][384]  @ 1671168   (gathered x, bf16 token-major)
//   fused[65536][2304] @ 26836992  (q | kv | StarReLU(ff)); q overwritten by x_attn
//   gate [65536][16]   @ 177831936
#define OFF_WG 884736
#define OFF_WAO 933888
#define OFF_WFO 1081344
#define OFF_XG 1671168
#define OFF_FUSED 26836992
#define OFF_GATE 177831936
#define WS_NEED 357761024ull

__global__ __launch_bounds__(256) void prep_weights(
    const float* __restrict__ wf, const float* __restrict__ wg,
    const float* __restrict__ wao, const float* __restrict__ wfo,
    unsigned short* __restrict__ ws) {
  int i = blockIdx.x * 256 + threadIdx.x;
  if (i < 884736) { ws[i] = f2bf(wf[i]); return; }
  int j = i - 884736;
  if (j < 49152) { ws[i] = f2bf(j < 4608 ? wg[j] : 0.0f); return; }
  j -= 49152;
  if (j < 147456) { ws[i] = f2bf(wao[j]); return; }
  j -= 147456;
  if (j < 589824) ws[i] = f2bf(wfo[j]);
}

// ---- k0: gather NCHW fp32 -> token-major bf16 xg [65536][384] ----
__global__ __launch_bounds__(256) void k0_gather(const float* __restrict__ x,
                                                 unsigned short* __restrict__ xg) {
  __shared__ __align__(16) char As[49152];
  int tid = threadIdx.x, wi = blockIdx.x;
  int b = wi >> 6, ghi = (wi >> 3) & 7, gwi = wi & 7;
  const float* xb = x + (size_t)b * 1572864 + (ghi * 8) * 64 + gwi * 8;
  for (int it = 0; it < 12; ++it) {
    int idx = it * 256 + tid;  // (c, p1)
    int c = idx % 384, p1 = idx / 384;
    const float* src = xb + (size_t)c * 4096 + p1 * 64;
    float4 v0 = *(const float4*)src, v1 = *(const float4*)(src + 4);
    float f[8] = {v0.x, v0.y, v0.z, v0.w, v1.x, v1.y, v1.z, v1.w};
#pragma unroll
    for (int jj = 0; jj < 8; ++jj) {
      int row = p1 * 8 + jj;
      int byte = (row * 768 + c * 2) ^ ((row & 7) << 4);
      *(ushort_a*)(As + byte) = f2bf(f[jj]);
    }
  }
  __syncthreads();
  unsigned short* og = xg + (size_t)wi * 24576;
#pragma unroll
  for (int it = 0; it < 12; ++it) {
    int idx = it * 256 + tid;
    int row = idx / 48, c = idx % 48;
    int byte = (row * 768 + c * 16) ^ ((row & 7) << 4);
    *(us8*)(og + (size_t)row * 384 + c * 8) = *(us8*)(As + byte);
  }
}

// ---- k1: fused = xg . W_fused^T  (M=65536, N=2304 + gate 16, K=384) ----
// grid 512*19, mb-major XCD-chunked: consecutive blocks share the A-tile
// (xg read ~once from HBM); nb 0..17 -> fused cols (StarReLU nb>=6); 18 -> gate
__global__ __launch_bounds__(512, 4) void k1_gemm(unsigned short* __restrict__ ws,
                                                  const float* __restrict__ srs,
                                                  const float* __restrict__ srb) {
  __shared__ __align__(16) char sm[65536];  // A bufs @0/16384, B bufs @32768/49152
  const int tid = threadIdx.x, lane = tid & 63, wave = tid >> 6;
  const int l15 = lane & 15, l4 = lane >> 4;
  const int wr = wave & 3, wc = wave >> 2;
  // bijective XCD-chunked mb-major remap: 9728 = 8 * 1216
  const int bid = blockIdx.x;
  const int swz = (bid & 7) * 1216 + (bid >> 3);
  const int mb = swz / 19, nb = swz - mb * 19;
  const unsigned short* Ab = ws + OFF_XG + (size_t)mb * 128 * 384;
  const unsigned short* Bb =
      (nb < 18) ? ws + (size_t)nb * 128 * 384 : ws + OFF_WG;
  const int srow = tid >> 3, sc = tid & 7;
  f32x4 of[2][4] = {};
  us8 stA[2], stB[2];
#pragma unroll
  for (int r2 = 0; r2 < 2; ++r2) {
    int row = srow + 64 * r2;
    stA[r2] = *(const us8*)(Ab + (size_t)row * 384 + sc * 8);
    stB[r2] = *(const us8*)(Bb + (size_t)row * 384 + sc * 8);
  }
#pragma unroll
  for (int r2 = 0; r2 < 2; ++r2) {
    int row = srow + 64 * r2;
    int byte = (row * 128 + sc * 16) ^ ((row & 7) << 4);
    *(us8*)(sm + byte) = stA[r2];
    *(us8*)(sm + 32768 + byte) = stB[r2];
  }
  __syncthreads();
#pragma unroll 1
  for (int ks = 0; ks < 6; ++ks) {
    int cur = (ks & 1) * 16384;
    if (ks < 5) {
#pragma unroll
      for (int r2 = 0; r2 < 2; ++r2) {
        int row = srow + 64 * r2;
        stA[r2] = *(const us8*)(Ab + (size_t)row * 384 + (ks + 1) * 64 + sc * 8);
        stB[r2] = *(const us8*)(Bb + (size_t)row * 384 + (ks + 1) * 64 + sc * 8);
      }
    }
#pragma unroll
    for (int kk = 0; kk < 2; ++kk) {
      bf16x8 af[2], bfr[4];
#pragma unroll
      for (int mt = 0; mt < 2; ++mt) {
        int row = wr * 32 + mt * 16 + l15;
        af[mt] = *(const bf16x8*)(sm + cur +
                                  ((row * 128 + kk * 64 + l4 * 16) ^ ((row & 7) << 4)));
      }
#pragma unroll
      for (int nt = 0; nt < 4; ++nt) {
        int row = wc * 64 + nt * 16 + l15;
        bfr[nt] = *(const bf16x8*)(sm + 32768 + cur +
                                   ((row * 128 + kk * 64 + l4 * 16) ^ ((row & 7) << 4)));
      }
#pragma unroll
      for (int mt = 0; mt < 2; ++mt)
#pragma unroll
        for (int nt = 0; nt < 4; ++nt)
          of[mt][nt] = MFMA(af[mt], bfr[nt], of[mt][nt]);
    }
    if (ks < 5) {
      int nxt = ((ks + 1) & 1) * 16384;
#pragma unroll
      for (int r2 = 0; r2 < 2; ++r2) {
        int row = srow + 64 * r2;
        int byte = (row * 128 + sc * 16) ^ ((row & 7) << 4);
        *(us8*)(sm + nxt + byte) = stA[r2];
        *(us8*)(sm + 32768 + nxt + byte) = stB[r2];
      }
    }
    __syncthreads();
  }
  // epilogue: accs -> LDS bf16 [128][256B] swz -> coalesced NT global store
  const float ssc = srs[0], sbi = srb[0];
  const bool ffreg = (nb >= 6) && (nb < 18);
#pragma unroll
  for (int mt = 0; mt < 2; ++mt)
#pragma unroll
    for (int nt = 0; nt < 4; ++nt)
#pragma unroll
      for (int rr = 0; rr < 4; ++rr) {
        int row = wr * 32 + mt * 16 + l4 * 4 + rr;
        int col = wc * 64 + nt * 16 + l15;
        float v = of[mt][nt][rr];
        if (ffreg) { v = fmaxf(v, 0.0f); v = ssc * v * v + sbi; }
        *(ushort_a*)(sm + ((row * 256 + col * 2) ^ ((row & 7) << 4))) = f2bf(v);
      }
  __syncthreads();
  if (nb < 18) {
    unsigned short* fo = ws + OFF_FUSED + (size_t)mb * 128 * 2304 + nb * 128;
#pragma unroll
    for (int r2 = 0; r2 < 4; ++r2) {
      int idx = r2 * 512 + tid;
      int row = idx >> 4, c = idx & 15;
      int byte = (row * 256 + c * 16) ^ ((row & 7) << 4);
      __builtin_nontemporal_store(*(us8*)(sm + byte),
                                  (us8*)(fo + (size_t)row * 2304 + c * 8));
    }
  } else {
    unsigned short* go = ws + OFF_GATE + (size_t)mb * 128 * 16;
#pragma unroll
    for (int r2 = 0; r2 < 4; ++r2) {
      int idx = r2 * 512 + tid;
      int row = idx >> 4, c = idx & 15;
      if (c < 2) {
        int byte = (row * 256 + c * 16) ^ ((row & 7) << 4);
        __builtin_nontemporal_store(*(us8*)(sm + byte),
                                    (us8*)(go + (size_t)row * 16 + c * 8));
      }
    }
  }
}

// ---- k2: windowed attention (per-wave private, no barriers) ----
// block = 1 window, 4 waves x 3 heads; writes gated x_attn over the q region.
__global__ __launch_bounds__(256, 3) void k2_attn(unsigned short* __restrict__ ws,
                                                  const float* __restrict__ bgate) {
  __shared__ __align__(16) char sm[49152];
  const int tid = threadIdx.x, lane = tid & 63, wave = tid >> 6;
  const int l15 = lane & 15, l4 = lane >> 4;
  char* kvT = sm + wave * 12288;  // [32 d][128B m]
  char* Pb = kvT + 4096;          // [64 n][128B m]
  const int wi = blockIdx.x;
  const size_t T0 = (size_t)wi * 64;
  unsigned short* fused = ws + OFF_FUSED;
  const unsigned short* gb = ws + OFF_GATE;
  const f32x4 zz = {};
#pragma unroll 1
  for (int hi = 0; hi < 3; ++hi) {
    const int h = wave + hi * 4;
    bf16x8 akv[4], bq[4];
#pragma unroll
    for (int t = 0; t < 4; ++t) {
      akv[t] = *(const bf16x8*)(fused + (T0 + t * 16 + l15) * 2304 + 384 + h * 32 + l4 * 8);
      bq[t] = *(const bf16x8*)(fused + (T0 + t * 16 + l15) * 2304 + h * 32 + l4 * 8);
    }
    // S^T[m][n] = sum_d kv[m][d] q[n][d]
    f32x4 sfT[4][4];
#pragma unroll
    for (int mt = 0; mt < 4; ++mt)
#pragma unroll
      for (int ni = 0; ni < 4; ++ni) sfT[mt][ni] = MFMA(akv[mt], bq[ni], zz);
    // kvT build (scalar scatter, per-wave private)
#pragma unroll
    for (int mt = 0; mt < 4; ++mt) {
      us8 u = __builtin_bit_cast(us8, akv[mt]);
      int m = mt * 16 + l15;
#pragma unroll
      for (int j = 0; j < 8; ++j) {
        int d = l4 * 8 + j;
        *(ushort_a*)(kvT + ((d * 128 + m * 2) ^ ((d & 7) << 4))) = u[j];
      }
    }
    // softmax over m (16 in-lane + shfl over lane bits 4,5); write P[n][m]
#pragma unroll
    for (int ni = 0; ni < 4; ++ni) {
      float s[16];
#pragma unroll
      for (int mt = 0; mt < 4; ++mt)
#pragma unroll
        for (int rr = 0; rr < 4; ++rr)
          s[mt * 4 + rr] = sfT[mt][ni][rr] * 0.176776695f;
      float mx = s[0];
#pragma unroll
      for (int q2 = 1; q2 < 16; ++q2) mx = fmaxf(mx, s[q2]);
      mx = fmaxf(mx, __shfl_xor(mx, 16, 64));
      mx = fmaxf(mx, __shfl_xor(mx, 32, 64));
      float sum = 0.0f;
#pragma unroll
      for (int q2 = 0; q2 < 16; ++q2) {
        s[q2] = __expf(s[q2] - mx);
        sum += s[q2];
      }
      sum += __shfl_xor(sum, 16, 64);
      sum += __shfl_xor(sum, 32, 64);
      float rs = 1.0f / sum;
      int n = ni * 16 + l15;
      int rowb = n * 128, sw = (n & 7) << 4;
#pragma unroll
      for (int mt = 0; mt < 4; ++mt) {
        int m = mt * 16 + l4 * 4;
        unsigned p0 = (unsigned)f2bf(s[mt * 4 + 0] * rs) |
                      ((unsigned)f2bf(s[mt * 4 + 1] * rs) << 16);
        unsigned p1 = (unsigned)f2bf(s[mt * 4 + 2] * rs) |
                      ((unsigned)f2bf(s[mt * 4 + 3] * rs) << 16);
        *(uint_a*)(Pb + ((rowb + m * 2) ^ sw)) = p0;
        *(uint_a*)(Pb + ((rowb + (m + 2) * 2) ^ sw)) = p1;
      }
    }
    // PV: X[n][d]
    f32x4 xo[4][2] = {};
#pragma unroll
    for (int ks = 0; ks < 2; ++ks) {
      bf16x8 bv[2];
#pragma unroll
      for (int dt = 0; dt < 2; ++dt) {
        int d = dt * 16 + l15;
        bv[dt] = *(const bf16x8*)(kvT + ((d * 128 + ks * 64 + l4 * 16) ^ ((d & 7) << 4)));
      }
#pragma unroll
      for (int nt = 0; nt < 4; ++nt) {
        int n = nt * 16 + l15;
        bf16x8 ap = *(const bf16x8*)(Pb + ((n * 128 + ks * 64 + l4 * 16) ^ ((n & 7) << 4)));
        xo[nt][0] = MFMA(ap, bv[0], xo[nt][0]);
        xo[nt][1] = MFMA(ap, bv[1], xo[nt][1]);
      }
    }
    // gate + store gated x_attn into q slot
    const float bgh = bgate[h];
#pragma unroll
    for (int nt = 0; nt < 4; ++nt)
#pragma unroll
      for (int rr = 0; rr < 4; ++rr) {
        int n = nt * 16 + l4 * 4 + rr;
        float gv = bf2f(gb[(T0 + n) * 16 + h]) + bgh;
        float sg = 1.0f / (1.0f + __expf(-gv));
#pragma unroll
        for (int dt = 0; dt < 2; ++dt)
          fused[(T0 + n) * 2304 + h * 32 + dt * 16 + l15] =
              f2bf(xo[nt][dt][rr] * sg);
      }
  }
}

// ---- k3: out = Xattn . wao^T + F . wfo^T  (K=1920, NCHW epilogue) ----
// grid 512*3, mb-major XCD-chunked: the 3 nb-blocks of one mb run together
// so the 576 KB A-panel is read from HBM ~once.
__global__ __launch_bounds__(512, 4) void k3_gemm(const unsigned short* __restrict__ ws,
                                                  float* __restrict__ out) {
  __shared__ __align__(16) char sm[65536];
  const int tid = threadIdx.x, lane = tid & 63, wave = tid >> 6;
  const int l15 = lane & 15, l4 = lane >> 4;
  const int wr = wave & 3, wc = wave >> 2;
  // bijective XCD-chunked mb-major remap: 1536 = 8 * 192
  const int bid = blockIdx.x;
  const int swz = (bid & 7) * 192 + (bid >> 3);
  const int mb = swz / 3, nB = swz - mb * 3;
  const size_t T0 = (size_t)mb * 128;
  const unsigned short* fA = ws + OFF_FUSED + T0 * 2304;
  const unsigned short* wao = ws + OFF_WAO + (size_t)(nB * 128) * 384;
  const unsigned short* wfo = ws + OFF_WFO + (size_t)(nB * 128) * 1536;
  const int srow = tid >> 3, sc = tid & 7;
  f32x4 of[2][4] = {};
  us8 stA[2], stB[2];
  auto loadAB = [&](int ks) {
    int ac = ks < 6 ? ks * 64 : 768 + (ks - 6) * 64;
#pragma unroll
    for (int r2 = 0; r2 < 2; ++r2) {
      int row = srow + 64 * r2;
      stA[r2] = *(const us8*)(fA + (size_t)row * 2304 + ac + sc * 8);
      if (ks < 6)
        stB[r2] = *(const us8*)(wao + (size_t)row * 384 + ks * 64 + sc * 8);
      else
        stB[r2] = *(const us8*)(wfo + (size_t)row * 1536 + (ks - 6) * 64 + sc * 8);
    }
  };
  auto writeAB = [&](int buf) {
#pragma unroll
    for (int r2 = 0; r2 < 2; ++r2) {
      int row = srow + 64 * r2;
      int byte = (row * 128 + sc * 16) ^ ((row & 7) << 4);
      *(us8*)(sm + buf + byte) = stA[r2];
      *(us8*)(sm + 32768 + buf + byte) = stB[r2];
    }
  };
  loadAB(0);
  writeAB(0);
  __syncthreads();
#pragma unroll 1
  for (int ks = 0; ks < 30; ++ks) {
    int cur = (ks & 1) * 16384;
    if (ks < 29) loadAB(ks + 1);
#pragma unroll
    for (int kk = 0; kk < 2; ++kk) {
      bf16x8 af[2], bfr[4];
#pragma unroll
      for (int mt = 0; mt < 2; ++mt) {
        int row = wr * 32 + mt * 16 + l15;
        af[mt] = *(const bf16x8*)(sm + cur +
                                  ((row * 128 + kk * 64 + l4 * 16) ^ ((row & 7) << 4)));
      }
#pragma unroll
      for (int nt = 0; nt < 4; ++nt) {
        int row = wc * 64 + nt * 16 + l15;
        bfr[nt] = *(const bf16x8*)(sm + 32768 + cur +
                                   ((row * 128 + kk * 64 + l4 * 16) ^ ((row & 7) << 4)));
      }
#pragma unroll
      for (int mt = 0; mt < 2; ++mt)
#pragma unroll
        for (int nt = 0; nt < 4; ++nt)
          of[mt][nt] = MFMA(af[mt], bfr[nt], of[mt][nt]);
    }
    if (ks < 29) writeAB(((ks + 1) & 1) * 16384);
    __syncthreads();
  }
  // epilogue: NCHW fp32 NT scatter
#pragma unroll
  for (int mt = 0; mt < 2; ++mt) {
    int n0 = wr * 32 + mt * 16 + l4 * 4;
    int T = (int)T0 + n0;
    int wi = T >> 6, n = T & 63;
    int b = wi >> 6, ghi = (wi >> 3) & 7, gwi = wi & 7;
    float* ob = out + (size_t)b * 1572864 + (size_t)(ghi * 8 + (n >> 3)) * 64 +
                gwi * 8 + (n & 7);
#pragma unroll
    for (int nt = 0; nt < 4; ++nt) {
      int c = nB * 128 + wc * 64 + nt * 16 + l15;
      __builtin_nontemporal_store(of[mt][nt], (f32x4*)(ob + (size_t)c * 4096));
    }
  }
}

// ---- fallback: round-6 fused kernel (weight offsets updated) ----
__global__ __launch_bounds__(512, 2) void fused_fallback(
    const float* __restrict__ x, const float* __restrict__ bgate,
    const float* __restrict__ srs, const float* __restrict__ srb,
    const unsigned short* __restrict__ wsb, float* __restrict__ out) {
  const unsigned short* wfB = wsb;
  const unsigned short* wgB = wsb + OFF_WG;
  const unsigned short* waoB = wsb + OFF_WAO;
  const unsigned short* wfoB = wsb + OFF_WFO;
  __shared__ __align__(16) char smem[114688];
  char* As = smem;
  char* Stg = smem + 98304;
  const int tid = threadIdx.x;
  const int lane = tid & 63, wave = tid >> 6;
  const int l15 = lane & 15, l4 = lane >> 4;
  const int pair = wave >> 1, nb = (wave & 1) * 32;
  char* PB = smem + 49152 + pair * 12288;
  char* KTb = PB + 8192;
  const int g = blockIdx.x;
  const int wi = (g & 7) * 128 + (g >> 3);
  const int b = wi >> 6, ghi = (wi >> 3) & 7, gwi = wi & 7;
  const int h0 = ghi * 8, w0 = gwi * 8;
  {
    const float* xb = x + (size_t)b * 1572864 + h0 * 64 + w0;
    for (int it = 0; it < 6; ++it) {
      int idx = it * 512 + tid;
      int c = idx % 384, p1 = idx / 384;
      const float* src = xb + (size_t)c * 4096 + p1 * 64;
      float4 v0 = *(const float4*)src;
      float4 v1 = *(const float4*)(src + 4);
      float f[8] = {v0.x, v0.y, v0.z, v0.w, v1.x, v1.y, v1.z, v1.w};
#pragma unroll
      for (int jj = 0; jj < 8; ++jj) {
        int row = p1 * 8 + jj;
        int byte = (row * 768 + c * 2) ^ ((row & 7) << 4);
        *(ushort_a*)(As + byte) = f2bf(f[jj]);
      }
    }
  }
  const float ss = srs[0], sbi = srb[0];
  __syncthreads();
  auto ldA = [&](int row, int ks) -> bf16x8 {
    int byte = (row * 768 + ks * 64 + l4 * 16) ^ ((row & 7) << 4);
    return *(const bf16x8*)(As + byte);
  };
  f32x4 gfr[2] = {};
  {
    const unsigned short* wg0 = wgB + (size_t)l15 * 384 + l4 * 8;
#pragma unroll 2
    for (int ks = 0; ks < 12; ++ks) {
      bf16x8 bg = *(const bf16x8*)(wg0 + ks * 32);
      bf16x8 a0 = ldA(nb + l15, ks), a1 = ldA(nb + 16 + l15, ks);
      gfr[0] = MFMA(a0, bg, gfr[0]);
      gfr[1] = MFMA(a1, bg, gfr[1]);
    }
    float gb = (l15 < 12) ? bgate[l15] : 0.0f;
    gfr[0] += gb;
    gfr[1] += gb;
  }
  f32x4 of[4][3] = {};
#pragma unroll 1
  for (int r = 0; r < 3; ++r) {
    const int h = r * 4 + pair;
    f32x4 qf[2][2] = {}, kf[2][2] = {};
    const unsigned short* wq = wfB + ((size_t)(h * 32) + l15) * 384 + l4 * 8;
    const unsigned short* wk = wq + (size_t)384 * 384;
#pragma unroll 2
    for (int ks = 0; ks < 12; ++ks) {
      bf16x8 a0 = ldA(nb + l15, ks), a1 = ldA(nb + 16 + l15, ks);
#pragma unroll
      for (int nt = 0; nt < 2; ++nt) {
        bf16x8 bq = *(const bf16x8*)(wq + (size_t)nt * 16 * 384 + ks * 32);
        bf16x8 bk = *(const bf16x8*)(wk + (size_t)nt * 16 * 384 + ks * 32);
        qf[0][nt] = MFMA(a0, bq, qf[0][nt]);
        qf[1][nt] = MFMA(a1, bq, qf[1][nt]);
        kf[0][nt] = MFMA(a0, bk, kf[0][nt]);
        kf[1][nt] = MFMA(a1, bk, kf[1][nt]);
      }
    }
#pragma unroll
    for (int mt = 0; mt < 2; ++mt)
#pragma unroll
      for (int nt = 0; nt < 2; ++nt)
#pragma unroll
        for (int rr = 0; rr < 4; ++rr) {
          int n = nb + mt * 16 + l4 * 4 + rr;
          int d = nt * 16 + l15;
          int sw = (n & 7) << 4;
          *(ushort_a*)(PB + ((n * 128 + d * 2) ^ sw)) =
              f2bf(qf[mt][nt][rr] * 0.176776695f);
          unsigned short kvv = f2bf(kf[mt][nt][rr]);
          *(ushort_a*)(PB + ((n * 128 + 64 + d * 2) ^ sw)) = kvv;
          *(ushort_a*)(KTb + ((d * 128 + n * 2) ^ ((d & 7) << 4))) = kvv;
        }
    __syncthreads();
    f32x4 sf[2][4] = {};
    {
      bf16x8 bkv[4];
#pragma unroll
      for (int ni = 0; ni < 4; ++ni) {
        int m = ni * 16 + l15;
        bkv[ni] = *(const bf16x8*)(PB + ((m * 128 + 64 + l4 * 16) ^ ((m & 7) << 4)));
      }
#pragma unroll
      for (int mt = 0; mt < 2; ++mt) {
        int n = nb + mt * 16 + l15;
        bf16x8 aq = *(const bf16x8*)(PB + ((n * 128 + l4 * 16) ^ ((n & 7) << 4)));
#pragma unroll
        for (int ni = 0; ni < 4; ++ni) sf[mt][ni] = MFMA(aq, bkv[ni], sf[mt][ni]);
      }
    }
    __syncthreads();
#pragma unroll
    for (int mt = 0; mt < 2; ++mt) {
#pragma unroll
      for (int rr = 0; rr < 4; ++rr) {
        float v0 = sf[mt][0][rr], v1 = sf[mt][1][rr], v2 = sf[mt][2][rr],
              v3 = sf[mt][3][rr];
        float mx = fmaxf(fmaxf(v0, v1), fmaxf(v2, v3));
        mx = fmaxf(mx, __shfl_xor(mx, 1, 64));
        mx = fmaxf(mx, __shfl_xor(mx, 2, 64));
        mx = fmaxf(mx, __shfl_xor(mx, 4, 64));
        mx = fmaxf(mx, __shfl_xor(mx, 8, 64));
        float e0 = __expf(v0 - mx), e1 = __expf(v1 - mx), e2 = __expf(v2 - mx),
              e3 = __expf(v3 - mx);
        float sm2 = e0 + e1 + e2 + e3;
        sm2 += __shfl_xor(sm2, 1, 64);
        sm2 += __shfl_xor(sm2, 2, 64);
        sm2 += __shfl_xor(sm2, 4, 64);
        sm2 += __shfl_xor(sm2, 8, 64);
        float rs = 1.0f / sm2;
        int n = nb + mt * 16 + l4 * 4 + rr;
        int base = n * 128, sw = (n & 7) << 4;
        *(ushort_a*)(PB + ((base + l15 * 2) ^ sw)) = f2bf(e0 * rs);
        *(ushort_a*)(PB + ((base + 32 + l15 * 2) ^ sw)) = f2bf(e1 * rs);
        *(ushort_a*)(PB + ((base + 64 + l15 * 2) ^ sw)) = f2bf(e2 * rs);
        *(ushort_a*)(PB + ((base + 96 + l15 * 2) ^ sw)) = f2bf(e3 * rs);
      }
    }
    f32x4 xo[2][2] = {};
#pragma unroll
    for (int ks = 0; ks < 2; ++ks) {
      bf16x8 bv[2];
#pragma unroll
      for (int nt = 0; nt < 2; ++nt) {
        int d = nt * 16 + l15;
        bv[nt] = *(const bf16x8*)(KTb + ((d * 128 + ks * 64 + l4 * 16) ^ ((d & 7) << 4)));
      }
#pragma unroll
      for (int mt = 0; mt < 2; ++mt) {
        int n = nb + mt * 16 + l15;
        bf16x8 ap = *(const bf16x8*)(PB + ((n * 128 + ks * 64 + l4 * 16) ^ ((n & 7) << 4)));
        xo[mt][0] = MFMA(ap, bv[0], xo[mt][0]);
        xo[mt][1] = MFMA(ap, bv[1], xo[mt][1]);
      }
    }
#pragma unroll
    for (int mt = 0; mt < 2; ++mt) {
#pragma unroll
      for (int rr = 0; rr < 4; ++rr) {
        float gv = __shfl(gfr[mt][rr], (lane & 48) | h, 64);
        float sg = 1.0f / (1.0f + __expf(-gv));
        int n = nb + mt * 16 + l4 * 4 + rr;
        int sw = (n & 7) << 4;
        int c0 = pair * 32 + l15;
        *(ushort_a*)(Stg + ((n * 256 + c0 * 2) ^ sw)) = f2bf(xo[mt][0][rr] * sg);
        *(ushort_a*)(Stg + ((n * 256 + (c0 + 16) * 2) ^ sw)) = f2bf(xo[mt][1][rr] * sg);
      }
    }
    __syncthreads();
    {
      const unsigned short* wao0 =
          waoB + (size_t)(wave * 48 + l15) * 384 + r * 128 + l4 * 8;
#pragma unroll
      for (int ks = 0; ks < 4; ++ks) {
        int kb = ks * 64 + l4 * 16, sz = (l15 & 7) << 4;
        bf16x8 a0 = *(const bf16x8*)(Stg + ((l15 * 256 + kb) ^ sz));
        bf16x8 a1 = *(const bf16x8*)(Stg + (((16 + l15) * 256 + kb) ^ sz));
        bf16x8 a2 = *(const bf16x8*)(Stg + (((32 + l15) * 256 + kb) ^ sz));
        bf16x8 a3 = *(const bf16x8*)(Stg + (((48 + l15) * 256 + kb) ^ sz));
#pragma unroll
        for (int nt = 0; nt < 3; ++nt) {
          bf16x8 bw = *(const bf16x8*)(wao0 + (size_t)nt * 16 * 384 + ks * 32);
          of[0][nt] = MFMA(a0, bw, of[0][nt]);
          of[1][nt] = MFMA(a1, bw, of[1][nt]);
          of[2][nt] = MFMA(a2, bw, of[2][nt]);
          of[3][nt] = MFMA(a3, bw, of[3][nt]);
        }
      }
    }
  }
#pragma unroll 1
  for (int tg = 0; tg < 6; ++tg) {
    f32x4 ffr[4][2] = {};
    const unsigned short* wfin0 =
        wfB + (size_t)(768 + tg * 256 + wave * 16 + l15) * 384 + l4 * 8;
    const unsigned short* wfin1 = wfin0 + (size_t)128 * 384;
#pragma unroll 2
    for (int ks = 0; ks < 12; ++ks) {
      bf16x8 a0 = ldA(l15, ks), a1 = ldA(16 + l15, ks), a2 = ldA(32 + l15, ks),
             a3 = ldA(48 + l15, ks);
      bf16x8 bw0 = *(const bf16x8*)(wfin0 + ks * 32);
      ffr[0][0] = MFMA(a0, bw0, ffr[0][0]);
      ffr[1][0] = MFMA(a1, bw0, ffr[1][0]);
      ffr[2][0] = MFMA(a2, bw0, ffr[2][0]);
      ffr[3][0] = MFMA(a3, bw0, ffr[3][0]);
      bf16x8 bw1 = *(const bf16x8*)(wfin1 + ks * 32);
      ffr[0][1] = MFMA(a0, bw1, ffr[0][1]);
      ffr[1][1] = MFMA(a1, bw1, ffr[1][1]);
      ffr[2][1] = MFMA(a2, bw1, ffr[2][1]);
      ffr[3][1] = MFMA(a3, bw1, ffr[3][1]);
    }
#pragma unroll
    for (int u = 0; u < 2; ++u) {
      char* fb = smem + 49152 + u * 16384;
#pragma unroll
      for (int mt = 0; mt < 4; ++mt)
#pragma unroll
        for (int rr = 0; rr < 4; ++rr) {
          float v = fmaxf(ffr[mt][u][rr], 0.0f);
          v = ss * v * v + sbi;
          int n = mt * 16 + l4 * 4 + rr;
          int cw = wave * 16 + l15;
          *(ushort_a*)(fb + ((n * 256 + cw * 2) ^ ((n & 7) << 4))) = f2bf(v);
        }
    }
    __syncthreads();
#pragma unroll 1
    for (int u = 0; u < 2; ++u) {
      char* fb = smem + 49152 + u * 16384;
      const unsigned short* wfo2 =
          wfoB + (size_t)(wave * 48 + l15) * 1536 + (tg * 2 + u) * 128 + l4 * 8;
#pragma unroll
      for (int ks = 0; ks < 4; ++ks) {
        int kb = ks * 64 + l4 * 16, sz = (l15 & 7) << 4;
        bf16x8 a0 = *(const bf16x8*)(fb + ((l15 * 256 + kb) ^ sz));
        bf16x8 a1 = *(const bf16x8*)(fb + (((16 + l15) * 256 + kb) ^ sz));
        bf16x8 a2 = *(const bf16x8*)(fb + (((32 + l15) * 256 + kb) ^ sz));
        bf16x8 a3 = *(const bf16x8*)(fb + (((48 + l15) * 256 + kb) ^ sz));
#pragma unroll
        for (int nt = 0; nt < 3; ++nt) {
          bf16x8 bw = *(const bf16x8*)(wfo2 + (size_t)nt * 16 * 1536 + ks * 32);
          of[0][nt] = MFMA(a0, bw, of[0][nt]);
          of[1][nt] = MFMA(a1, bw, of[1][nt]);
          of[2][nt] = MFMA(a2, bw, of[2][nt]);
          of[3][nt] = MFMA(a3, bw, of[3][nt]);
        }
      }
    }
    __syncthreads();
  }
  float* ob = out + (size_t)b * 1572864 + h0 * 64 + w0;
#pragma unroll
  for (int nt = 0; nt < 3; ++nt) {
    int col = wave * 48 + nt * 16 + l15;
    float* oc = ob + (size_t)col * 4096;
#pragma unroll
    for (int mt = 0; mt < 4; ++mt) {
      int n0 = mt * 16 + l4 * 4;
      *(f32x4*)(oc + (n0 >> 3) * 64 + (n0 & 7)) = of[mt][nt];
    }
  }
}

extern "C" void kernel_launch(void* const* d_in, const int* in_sizes, int n_in,
                              void* d_out, int out_size, void* d_ws, size_t ws_size,
                              hipStream_t stream) {
  const float* x = (const float*)d_in[0];
  const float* wf = (const float*)d_in[1];
  const float* wg = (const float*)d_in[2];
  const float* bg = (const float*)d_in[3];
  const float* wao = (const float*)d_in[4];
  const float* wfo = (const float*)d_in[5];
  const float* srs = (const float*)d_in[6];
  const float* srb = (const float*)d_in[7];
  unsigned short* ws = (unsigned short*)d_ws;

  prep_weights<<<6528, 256, 0, stream>>>(wf, wg, wao, wfo, ws);
  if (ws_size >= WS_NEED) {
    k0_gather<<<1024, 256, 0, stream>>>(x, ws + OFF_XG);
    k1_gemm<<<512 * 19, 512, 0, stream>>>(ws, srs, srb);
    k2_attn<<<1024, 256, 0, stream>>>(ws, bg);
    k3_gemm<<<512 * 3, 512, 0, stream>>>(ws, (float*)d_out);
  } else {
    fused_fallback<<<1024, 512, 0, stream>>>(x, bg, srs, srb, ws, (float*)d_out);
  }
}

// Round 11
// 495.571 us; speedup vs baseline: 1.3841x; 1.0079x over previous
//
#include <hip/hip_runtime.h>
#include <hip/hip_bf16.h>

// ---- types ----
typedef __bf16 bf16x8 __attribute__((ext_vector_type(8), may_alias));
typedef float f32x4 __attribute__((ext_vector_type(4), may_alias));
typedef unsigned short ushort_a __attribute__((may_alias));
typedef unsigned int uint_a __attribute__((may_alias));
typedef unsigned short us8 __attribute__((ext_vector_type(8), may_alias));

#define MFMA(a, b, c) __builtin_amdgcn_mfma_f32_16x16x32_bf16(a, b, c, 0, 0, 0)

__device__ __forceinline__ unsigned short f2bf(float f) {
  return __builtin_bit_cast(unsigned short, (__bf16)f);
}
__device__ __forceinline__ float bf2f(unsigned short u) {
  unsigned v = ((unsigned)u) << 16;
  return __builtin_bit_cast(float, v);
}

// ws layout (ushort elements):
//   wfB  [2304][384] @ 0
//   wgB  [128][384]  @ 884736    (rows >=12 zero)
//   waoB [384][384]  @ 933888
//   wfoB [384][1536] @ 1081344
//   xg   [65536][384]  @ 1671168   (gathered x, bf16 token-major)
//   fused[65536][2304] @ 26836992  (q | kv | StarReLU(ff)); q overwritten by x_attn
//   gate [65536][16]   @ 177831936
#define OFF_WG 884736
#define OFF_WAO 933888
#define OFF_WFO 1081344
#define OFF_XG 1671168
#define OFF_FUSED 26836992
#define OFF_GATE 177831936
#define WS_NEED 357761024ull

__global__ __launch_bounds__(256) void prep_weights(
    const float* __restrict__ wf, const float* __restrict__ wg,
    const float* __restrict__ wao, const float* __restrict__ wfo,
    unsigned short* __restrict__ ws) {
  int i = blockIdx.x * 256 + threadIdx.x;
  if (i < 884736) { ws[i] = f2bf(wf[i]); return; }
  int j = i - 884736;
  if (j < 49152) { ws[i] = f2bf(j < 4608 ? wg[j] : 0.0f); return; }
  j -= 49152;
  if (j < 147456) { ws[i] = f2bf(wao[j]); return; }
  j -= 147456;
  if (j < 589824) ws[i] = f2bf(wfo[j]);
}

// ---- k0: gather NCHW fp32 -> token-major bf16 xg [65536][384] ----
__global__ __launch_bounds__(256) void k0_gather(const float* __restrict__ x,
                                                 unsigned short* __restrict__ xg) {
  __shared__ __align__(16) char As[49152];
  int tid = threadIdx.x, wi = blockIdx.x;
  int b = wi >> 6, ghi = (wi >> 3) & 7, gwi = wi & 7;
  const float* xb = x + (size_t)b * 1572864 + (ghi * 8) * 64 + gwi * 8;
  for (int it = 0; it < 12; ++it) {
    int idx = it * 256 + tid;  // (c, p1)
    int c = idx % 384, p1 = idx / 384;
    const float* src = xb + (size_t)c * 4096 + p1 * 64;
    float4 v0 = *(const float4*)src, v1 = *(const float4*)(src + 4);
    float f[8] = {v0.x, v0.y, v0.z, v0.w, v1.x, v1.y, v1.z, v1.w};
#pragma unroll
    for (int jj = 0; jj < 8; ++jj) {
      int row = p1 * 8 + jj;
      int byte = (row * 768 + c * 2) ^ ((row & 7) << 4);
      *(ushort_a*)(As + byte) = f2bf(f[jj]);
    }
  }
  __syncthreads();
  unsigned short* og = xg + (size_t)wi * 24576;
#pragma unroll
  for (int it = 0; it < 12; ++it) {
    int idx = it * 256 + tid;
    int row = idx / 48, c = idx % 48;
    int byte = (row * 768 + c * 16) ^ ((row & 7) << 4);
    *(us8*)(og + (size_t)row * 384 + c * 8) = *(us8*)(As + byte);
  }
}

// ---- k1: fused = xg . W_fused^T  (M=65536, N=2304 + gate 16, K=384) ----
// mb-major XCD-chunked grid + 2-deep register prefetch pipeline.
__global__ __launch_bounds__(512, 4) void k1_gemm(unsigned short* __restrict__ ws,
                                                  const float* __restrict__ srs,
                                                  const float* __restrict__ srb) {
  __shared__ __align__(16) char sm[65536];  // A bufs @0/16384, B bufs @32768/49152
  const int tid = threadIdx.x, lane = tid & 63, wave = tid >> 6;
  const int l15 = lane & 15, l4 = lane >> 4;
  const int wr = wave & 3, wc = wave >> 2;
  // bijective XCD-chunked mb-major remap: 9728 = 8 * 1216
  const int bid = blockIdx.x;
  const int swz = (bid & 7) * 1216 + (bid >> 3);
  const int mb = swz / 19, nb = swz - mb * 19;
  const unsigned short* Ab = ws + OFF_XG + (size_t)mb * 128 * 384;
  const unsigned short* Bb =
      (nb < 18) ? ws + (size_t)nb * 128 * 384 : ws + OFF_WG;
  const int srow = tid >> 3, sc = tid & 7;
  f32x4 of[2][4] = {};
  us8 sA0[2], sB0[2], sA1[2], sB1[2];

#define K1_LOAD(KS, SA, SB)                                                   \
  {                                                                           \
    _Pragma("unroll") for (int r2 = 0; r2 < 2; ++r2) {                        \
      int row = srow + 64 * r2;                                               \
      SA[r2] = *(const us8*)(Ab + (size_t)row * 384 + (KS)*64 + sc * 8);      \
      SB[r2] = *(const us8*)(Bb + (size_t)row * 384 + (KS)*64 + sc * 8);      \
    }                                                                         \
  }
#define K1_WRITE(BUF, SA, SB)                                                 \
  {                                                                           \
    _Pragma("unroll") for (int r2 = 0; r2 < 2; ++r2) {                        \
      int row = srow + 64 * r2;                                               \
      int byte = ((row * 128 + sc * 16) ^ ((row & 7) << 4)) + (BUF);          \
      *(us8*)(sm + byte) = SA[r2];                                            \
      *(us8*)(sm + 32768 + byte) = SB[r2];                                    \
    }                                                                         \
  }
#define K1_COMPUTE(BUF)                                                       \
  {                                                                           \
    _Pragma("unroll") for (int kk = 0; kk < 2; ++kk) {                        \
      bf16x8 af[2], bfr[4];                                                   \
      _Pragma("unroll") for (int mt = 0; mt < 2; ++mt) {                      \
        int row = wr * 32 + mt * 16 + l15;                                    \
        af[mt] = *(const bf16x8*)(sm + (BUF) +                                \
                 ((row * 128 + kk * 64 + l4 * 16) ^ ((row & 7) << 4)));       \
      }                                                                       \
      _Pragma("unroll") for (int nt = 0; nt < 4; ++nt) {                      \
        int row = wc * 64 + nt * 16 + l15;                                    \
        bfr[nt] = *(const bf16x8*)(sm + 32768 + (BUF) +                       \
                  ((row * 128 + kk * 64 + l4 * 16) ^ ((row & 7) << 4)));      \
      }                                                                       \
      _Pragma("unroll") for (int mt = 0; mt < 2; ++mt)                        \
      _Pragma("unroll") for (int nt = 0; nt < 4; ++nt)                        \
          of[mt][nt] = MFMA(af[mt], bfr[nt], of[mt][nt]);                     \
    }                                                                         \
  }

  K1_LOAD(0, sA0, sB0);
  K1_LOAD(1, sA1, sB1);
  K1_WRITE(0, sA0, sB0);
  __syncthreads();
#pragma unroll 1
  for (int kp = 0; kp < 3; ++kp) {
    int ks = kp * 2;
    if (ks + 2 < 6) K1_LOAD(ks + 2, sA0, sB0);
    K1_COMPUTE(0);
    K1_WRITE(16384, sA1, sB1);
    __syncthreads();
    if (ks + 3 < 6) K1_LOAD(ks + 3, sA1, sB1);
    K1_COMPUTE(16384);
    if (ks + 2 < 6) K1_WRITE(0, sA0, sB0);
    __syncthreads();
  }
  // epilogue: accs -> LDS bf16 [128][256B] swz -> coalesced NT global store
  const float ssc = srs[0], sbi = srb[0];
  const bool ffreg = (nb >= 6) && (nb < 18);
#pragma unroll
  for (int mt = 0; mt < 2; ++mt)
#pragma unroll
    for (int nt = 0; nt < 4; ++nt)
#pragma unroll
      for (int rr = 0; rr < 4; ++rr) {
        int row = wr * 32 + mt * 16 + l4 * 4 + rr;
        int col = wc * 64 + nt * 16 + l15;
        float v = of[mt][nt][rr];
        if (ffreg) { v = fmaxf(v, 0.0f); v = ssc * v * v + sbi; }
        *(ushort_a*)(sm + ((row * 256 + col * 2) ^ ((row & 7) << 4))) = f2bf(v);
      }
  __syncthreads();
  if (nb < 18) {
    unsigned short* fo = ws + OFF_FUSED + (size_t)mb * 128 * 2304 + nb * 128;
#pragma unroll
    for (int r2 = 0; r2 < 4; ++r2) {
      int idx = r2 * 512 + tid;
      int row = idx >> 4, c = idx & 15;
      int byte = (row * 256 + c * 16) ^ ((row & 7) << 4);
      __builtin_nontemporal_store(*(us8*)(sm + byte),
                                  (us8*)(fo + (size_t)row * 2304 + c * 8));
    }
  } else {
    unsigned short* go = ws + OFF_GATE + (size_t)mb * 128 * 16;
#pragma unroll
    for (int r2 = 0; r2 < 4; ++r2) {
      int idx = r2 * 512 + tid;
      int row = idx >> 4, c = idx & 15;
      if (c < 2) {
        int byte = (row * 256 + c * 16) ^ ((row & 7) << 4);
        __builtin_nontemporal_store(*(us8*)(sm + byte),
                                    (us8*)(go + (size_t)row * 16 + c * 8));
      }
    }
  }
}

// ---- k2: windowed attention (per-wave private, no barriers) ----
__global__ __launch_bounds__(256, 3) void k2_attn(unsigned short* __restrict__ ws,
                                                  const float* __restrict__ bgate) {
  __shared__ __align__(16) char sm[49152];
  const int tid = threadIdx.x, lane = tid & 63, wave = tid >> 6;
  const int l15 = lane & 15, l4 = lane >> 4;
  char* kvT = sm + wave * 12288;  // [32 d][128B m]
  char* Pb = kvT + 4096;          // [64 n][128B m]
  const int wi = blockIdx.x;
  const size_t T0 = (size_t)wi * 64;
  unsigned short* fused = ws + OFF_FUSED;
  const unsigned short* gb = ws + OFF_GATE;
  const f32x4 zz = {};
#pragma unroll 1
  for (int hi = 0; hi < 3; ++hi) {
    const int h = wave + hi * 4;
    bf16x8 akv[4], bq[4];
#pragma unroll
    for (int t = 0; t < 4; ++t) {
      akv[t] = *(const bf16x8*)(fused + (T0 + t * 16 + l15) * 2304 + 384 + h * 32 + l4 * 8);
      bq[t] = *(const bf16x8*)(fused + (T0 + t * 16 + l15) * 2304 + h * 32 + l4 * 8);
    }
    // S^T[m][n] = sum_d kv[m][d] q[n][d]
    f32x4 sfT[4][4];
#pragma unroll
    for (int mt = 0; mt < 4; ++mt)
#pragma unroll
      for (int ni = 0; ni < 4; ++ni) sfT[mt][ni] = MFMA(akv[mt], bq[ni], zz);
    // kvT build (scalar scatter, per-wave private)
#pragma unroll
    for (int mt = 0; mt < 4; ++mt) {
      us8 u = __builtin_bit_cast(us8, akv[mt]);
      int m = mt * 16 + l15;
#pragma unroll
      for (int j = 0; j < 8; ++j) {
        int d = l4 * 8 + j;
        *(ushort_a*)(kvT + ((d * 128 + m * 2) ^ ((d & 7) << 4))) = u[j];
      }
    }
    // softmax over m (16 in-lane + shfl over lane bits 4,5); write P[n][m]
#pragma unroll
    for (int ni = 0; ni < 4; ++ni) {
      float s[16];
#pragma unroll
      for (int mt = 0; mt < 4; ++mt)
#pragma unroll
        for (int rr = 0; rr < 4; ++rr)
          s[mt * 4 + rr] = sfT[mt][ni][rr] * 0.176776695f;
      float mx = s[0];
#pragma unroll
      for (int q2 = 1; q2 < 16; ++q2) mx = fmaxf(mx, s[q2]);
      mx = fmaxf(mx, __shfl_xor(mx, 16, 64));
      mx = fmaxf(mx, __shfl_xor(mx, 32, 64));
      float sum = 0.0f;
#pragma unroll
      for (int q2 = 0; q2 < 16; ++q2) {
        s[q2] = __expf(s[q2] - mx);
        sum += s[q2];
      }
      sum += __shfl_xor(sum, 16, 64);
      sum += __shfl_xor(sum, 32, 64);
      float rs = 1.0f / sum;
      int n = ni * 16 + l15;
      int rowb = n * 128, sw = (n & 7) << 4;
#pragma unroll
      for (int mt = 0; mt < 4; ++mt) {
        int m = mt * 16 + l4 * 4;
        unsigned p0 = (unsigned)f2bf(s[mt * 4 + 0] * rs) |
                      ((unsigned)f2bf(s[mt * 4 + 1] * rs) << 16);
        unsigned p1 = (unsigned)f2bf(s[mt * 4 + 2] * rs) |
                      ((unsigned)f2bf(s[mt * 4 + 3] * rs) << 16);
        *(uint_a*)(Pb + ((rowb + m * 2) ^ sw)) = p0;
        *(uint_a*)(Pb + ((rowb + (m + 2) * 2) ^ sw)) = p1;
      }
    }
    // PV: X[n][d]
    f32x4 xo[4][2] = {};
#pragma unroll
    for (int ks = 0; ks < 2; ++ks) {
      bf16x8 bv[2];
#pragma unroll
      for (int dt = 0; dt < 2; ++dt) {
        int d = dt * 16 + l15;
        bv[dt] = *(const bf16x8*)(kvT + ((d * 128 + ks * 64 + l4 * 16) ^ ((d & 7) << 4)));
      }
#pragma unroll
      for (int nt = 0; nt < 4; ++nt) {
        int n = nt * 16 + l15;
        bf16x8 ap = *(const bf16x8*)(Pb + ((n * 128 + ks * 64 + l4 * 16) ^ ((n & 7) << 4)));
        xo[nt][0] = MFMA(ap, bv[0], xo[nt][0]);
        xo[nt][1] = MFMA(ap, bv[1], xo[nt][1]);
      }
    }
    // gate + store gated x_attn into q slot
    const float bgh = bgate[h];
#pragma unroll
    for (int nt = 0; nt < 4; ++nt)
#pragma unroll
      for (int rr = 0; rr < 4; ++rr) {
        int n = nt * 16 + l4 * 4 + rr;
        float gv = bf2f(gb[(T0 + n) * 16 + h]) + bgh;
        float sg = 1.0f / (1.0f + __expf(-gv));
#pragma unroll
        for (int dt = 0; dt < 2; ++dt)
          fused[(T0 + n) * 2304 + h * 32 + dt * 16 + l15] =
              f2bf(xo[nt][dt][rr] * sg);
      }
  }
}

// ---- k3: out = Xattn . wao^T + F . wfo^T  (K=1920, NCHW epilogue) ----
// mb-major XCD-chunked grid + 2-deep register prefetch pipeline.
__global__ __launch_bounds__(512, 4) void k3_gemm(const unsigned short* __restrict__ ws,
                                                  float* __restrict__ out) {
  __shared__ __align__(16) char sm[65536];
  const int tid = threadIdx.x, lane = tid & 63, wave = tid >> 6;
  const int l15 = lane & 15, l4 = lane >> 4;
  const int wr = wave & 3, wc = wave >> 2;
  // bijective XCD-chunked mb-major remap: 1536 = 8 * 192
  const int bid = blockIdx.x;
  const int swz = (bid & 7) * 192 + (bid >> 3);
  const int mb = swz / 3, nB = swz - mb * 3;
  const size_t T0 = (size_t)mb * 128;
  const unsigned short* fA = ws + OFF_FUSED + T0 * 2304;
  const unsigned short* wao = ws + OFF_WAO + (size_t)(nB * 128) * 384;
  const unsigned short* wfo = ws + OFF_WFO + (size_t)(nB * 128) * 1536;
  const int srow = tid >> 3, sc = tid & 7;
  f32x4 of[2][4] = {};
  us8 sA0[2], sB0[2], sA1[2], sB1[2];

#define K3_LOAD(KS, SA, SB)                                                   \
  {                                                                           \
    int ac = (KS) < 6 ? (KS)*64 : 768 + ((KS)-6) * 64;                        \
    _Pragma("unroll") for (int r2 = 0; r2 < 2; ++r2) {                        \
      int row = srow + 64 * r2;                                               \
      SA[r2] = *(const us8*)(fA + (size_t)row * 2304 + ac + sc * 8);          \
      if ((KS) < 6)                                                           \
        SB[r2] = *(const us8*)(wao + (size_t)row * 384 + (KS)*64 + sc * 8);   \
      else                                                                    \
        SB[r2] =                                                              \
            *(const us8*)(wfo + (size_t)row * 1536 + ((KS)-6) * 64 + sc * 8); \
    }                                                                         \
  }
#define K3_WRITE(BUF, SA, SB)                                                 \
  {                                                                           \
    _Pragma("unroll") for (int r2 = 0; r2 < 2; ++r2) {                        \
      int row = srow + 64 * r2;                                               \
      int byte = ((row * 128 + sc * 16) ^ ((row & 7) << 4)) + (BUF);          \
      *(us8*)(sm + byte) = SA[r2];                                            \
      *(us8*)(sm + 32768 + byte) = SB[r2];                                    \
    }                                                                         \
  }
#define K3_COMPUTE(BUF)                                                       \
  {                                                                           \
    _Pragma("unroll") for (int kk = 0; kk < 2; ++kk) {                        \
      bf16x8 af[2], bfr[4];                                                   \
      _Pragma("unroll") for (int mt = 0; mt < 2; ++mt) {                      \
        int row = wr * 32 + mt * 16 + l15;                                    \
        af[mt] = *(const bf16x8*)(sm + (BUF) +                                \
                 ((row * 128 + kk * 64 + l4 * 16) ^ ((row & 7) << 4)));       \
      }                                                                       \
      _Pragma("unroll") for (int nt = 0; nt < 4; ++nt) {                      \
        int row = wc * 64 + nt * 16 + l15;                                    \
        bfr[nt] = *(const bf16x8*)(sm + 32768 + (BUF) +                       \
                  ((row * 128 + kk * 64 + l4 * 16) ^ ((row & 7) << 4)));      \
      }                                                                       \
      _Pragma("unroll") for (int mt = 0; mt < 2; ++mt)                        \
      _Pragma("unroll") for (int nt = 0; nt < 4; ++nt)                        \
          of[mt][nt] = MFMA(af[mt], bfr[nt], of[mt][nt]);                     \
    }                                                                         \
  }

  K3_LOAD(0, sA0, sB0);
  K3_LOAD(1, sA1, sB1);
  K3_WRITE(0, sA0, sB0);
  __syncthreads();
#pragma unroll 1
  for (int kp = 0; kp < 15; ++kp) {
    int ks = kp * 2;
    if (ks + 2 < 30) K3_LOAD(ks + 2, sA0, sB0);
    K3_COMPUTE(0);
    K3_WRITE(16384, sA1, sB1);
    __syncthreads();
    if (ks + 3 < 30) K3_LOAD(ks + 3, sA1, sB1);
    K3_COMPUTE(16384);
    if (ks + 2 < 30) K3_WRITE(0, sA0, sB0);
    __syncthreads();
  }
  // epilogue: NCHW fp32 NT scatter
#pragma unroll
  for (int mt = 0; mt < 2; ++mt) {
    int n0 = wr * 32 + mt * 16 + l4 * 4;
    int T = (int)T0 + n0;
    int wi = T >> 6, n = T & 63;
    int b = wi >> 6, ghi = (wi >> 3) & 7, gwi = wi & 7;
    float* ob = out + (size_t)b * 1572864 + (size_t)(ghi * 8 + (n >> 3)) * 64 +
                gwi * 8 + (n & 7);
#pragma unroll
    for (int nt = 0; nt < 4; ++nt) {
      int c = nB * 128 + wc * 64 + nt * 16 + l15;
      __builtin_nontemporal_store(of[mt][nt], (f32x4*)(ob + (size_t)c * 4096));
    }
  }
}

// ---- fallback: round-6 fused kernel (weight offsets updated) ----
__global__ __launch_bounds__(512, 2) void fused_fallback(
    const float* __restrict__ x, const float* __restrict__ bgate,
    const float* __restrict__ srs, const float* __restrict__ srb,
    const unsigned short* __restrict__ wsb, float* __restrict__ out) {
  const unsigned short* wfB = wsb;
  const unsigned short* wgB = wsb + OFF_WG;
  const unsigned short* waoB = wsb + OFF_WAO;
  const unsigned short* wfoB = wsb + OFF_WFO;
  __shared__ __align__(16) char smem[114688];
  char* As = smem;
  char* Stg = smem + 98304;
  const int tid = threadIdx.x;
  const int lane = tid & 63, wave = tid >> 6;
  const int l15 = lane & 15, l4 = lane >> 4;
  const int pair = wave >> 1, nb = (wave & 1) * 32;
  char* PB = smem + 49152 + pair * 12288;
  char* KTb = PB + 8192;
  const int g = blockIdx.x;
  const int wi = (g & 7) * 128 + (g >> 3);
  const int b = wi >> 6, ghi = (wi >> 3) & 7, gwi = wi & 7;
  const int h0 = ghi * 8, w0 = gwi * 8;
  {
    const float* xb = x + (size_t)b * 1572864 + h0 * 64 + w0;
    for (int it = 0; it < 6; ++it) {
      int idx = it * 512 + tid;
      int c = idx % 384, p1 = idx / 384;
      const float* src = xb + (size_t)c * 4096 + p1 * 64;
      float4 v0 = *(const float4*)src;
      float4 v1 = *(const float4*)(src + 4);
      float f[8] = {v0.x, v0.y, v0.z, v0.w, v1.x, v1.y, v1.z, v1.w};
#pragma unroll
      for (int jj = 0; jj < 8; ++jj) {
        int row = p1 * 8 + jj;
        int byte = (row * 768 + c * 2) ^ ((row & 7) << 4);
        *(ushort_a*)(As + byte) = f2bf(f[jj]);
      }
    }
  }
  const float ss = srs[0], sbi = srb[0];
  __syncthreads();
  auto ldA = [&](int row, int ks) -> bf16x8 {
    int byte = (row * 768 + ks * 64 + l4 * 16) ^ ((row & 7) << 4);
    return *(const bf16x8*)(As + byte);
  };
  f32x4 gfr[2] = {};
  {
    const unsigned short* wg0 = wgB + (size_t)l15 * 384 + l4 * 8;
#pragma unroll 2
    for (int ks = 0; ks < 12; ++ks) {
      bf16x8 bg = *(const bf16x8*)(wg0 + ks * 32);
      bf16x8 a0 = ldA(nb + l15, ks), a1 = ldA(nb + 16 + l15, ks);
      gfr[0] = MFMA(a0, bg, gfr[0]);
      gfr[1] = MFMA(a1, bg, gfr[1]);
    }
    float gb = (l15 < 12) ? bgate[l15] : 0.0f;
    gfr[0] += gb;
    gfr[1] += gb;
  }
  f32x4 of[4][3] = {};
#pragma unroll 1
  for (int r = 0; r < 3; ++r) {
    const int h = r * 4 + pair;
    f32x4 qf[2][2] = {}, kf[2][2] = {};
    const unsigned short* wq = wfB + ((size_t)(h * 32) + l15) * 384 + l4 * 8;
    const unsigned short* wk = wq + (size_t)384 * 384;
#pragma unroll 2
    for (int ks = 0; ks < 12; ++ks) {
      bf16x8 a0 = ldA(nb + l15, ks), a1 = ldA(nb + 16 + l15, ks);
#pragma unroll
      for (int nt = 0; nt < 2; ++nt) {
        bf16x8 bq = *(const bf16x8*)(wq + (size_t)nt * 16 * 384 + ks * 32);
        bf16x8 bk = *(const bf16x8*)(wk + (size_t)nt * 16 * 384 + ks * 32);
        qf[0][nt] = MFMA(a0, bq, qf[0][nt]);
        qf[1][nt] = MFMA(a1, bq, qf[1][nt]);
        kf[0][nt] = MFMA(a0, bk, kf[0][nt]);
        kf[1][nt] = MFMA(a1, bk, kf[1][nt]);
      }
    }
#pragma unroll
    for (int mt = 0; mt < 2; ++mt)
#pragma unroll
      for (int nt = 0; nt < 2; ++nt)
#pragma unroll
        for (int rr = 0; rr < 4; ++rr) {
          int n = nb + mt * 16 + l4 * 4 + rr;
          int d = nt * 16 + l15;
          int sw = (n & 7) << 4;
          *(ushort_a*)(PB + ((n * 128 + d * 2) ^ sw)) =
              f2bf(qf[mt][nt][rr] * 0.176776695f);
          unsigned short kvv = f2bf(kf[mt][nt][rr]);
          *(ushort_a*)(PB + ((n * 128 + 64 + d * 2) ^ sw)) = kvv;
          *(ushort_a*)(KTb + ((d * 128 + n * 2) ^ ((d & 7) << 4))) = kvv;
        }
    __syncthreads();
    f32x4 sf[2][4] = {};
    {
      bf16x8 bkv[4];
#pragma unroll
      for (int ni = 0; ni < 4; ++ni) {
        int m = ni * 16 + l15;
        bkv[ni] = *(const bf16x8*)(PB + ((m * 128 + 64 + l4 * 16) ^ ((m & 7) << 4)));
      }
#pragma unroll
      for (int mt = 0; mt < 2; ++mt) {
        int n = nb + mt * 16 + l15;
        bf16x8 aq = *(const bf16x8*)(PB + ((n * 128 + l4 * 16) ^ ((n & 7) << 4)));
#pragma unroll
        for (int ni = 0; ni < 4; ++ni) sf[mt][ni] = MFMA(aq, bkv[ni], sf[mt][ni]);
      }
    }
    __syncthreads();
#pragma unroll
    for (int mt = 0; mt < 2; ++mt) {
#pragma unroll
      for (int rr = 0; rr < 4; ++rr) {
        float v0 = sf[mt][0][rr], v1 = sf[mt][1][rr], v2 = sf[mt][2][rr],
              v3 = sf[mt][3][rr];
        float mx = fmaxf(fmaxf(v0, v1), fmaxf(v2, v3));
        mx = fmaxf(mx, __shfl_xor(mx, 1, 64));
        mx = fmaxf(mx, __shfl_xor(mx, 2, 64));
        mx = fmaxf(mx, __shfl_xor(mx, 4, 64));
        mx = fmaxf(mx, __shfl_xor(mx, 8, 64));
        float e0 = __expf(v0 - mx), e1 = __expf(v1 - mx), e2 = __expf(v2 - mx),
              e3 = __expf(v3 - mx);
        float sm2 = e0 + e1 + e2 + e3;
        sm2 += __shfl_xor(sm2, 1, 64);
        sm2 += __shfl_xor(sm2, 2, 64);
        sm2 += __shfl_xor(sm2, 4, 64);
        sm2 += __shfl_xor(sm2, 8, 64);
        float rs = 1.0f / sm2;
        int n = nb + mt * 16 + l4 * 4 + rr;
        int base = n * 128, sw = (n & 7) << 4;
        *(ushort_a*)(PB + ((base + l15 * 2) ^ sw)) = f2bf(e0 * rs);
        *(ushort_a*)(PB + ((base + 32 + l15 * 2) ^ sw)) = f2bf(e1 * rs);
        *(ushort_a*)(PB + ((base + 64 + l15 * 2) ^ sw)) = f2bf(e2 * rs);
        *(ushort_a*)(PB + ((base + 96 + l15 * 2) ^ sw)) = f2bf(e3 * rs);
      }
    }
    f32x4 xo[2][2] = {};
#pragma unroll
    for (int ks = 0; ks < 2; ++ks) {
      bf16x8 bv[2];
#pragma unroll
      for (int nt = 0; nt < 2; ++nt) {
        int d = nt * 16 + l15;
        bv[nt] = *(const bf16x8*)(KTb + ((d * 128 + ks * 64 + l4 * 16) ^ ((d & 7) << 4)));
      }
#pragma unroll
      for (int mt = 0; mt < 2; ++mt) {
        int n = nb + mt * 16 + l15;
        bf16x8 ap = *(const bf16x8*)(PB + ((n * 128 + ks * 64 + l4 * 16) ^ ((n & 7) << 4)));
        xo[mt][0] = MFMA(ap, bv[0], xo[mt][0]);
        xo[mt][1] = MFMA(ap, bv[1], xo[mt][1]);
      }
    }
#pragma unroll
    for (int mt = 0; mt < 2; ++mt) {
#pragma unroll
      for (int rr = 0; rr < 4; ++rr) {
        float gv = __shfl(gfr[mt][rr], (lane & 48) | h, 64);
        float sg = 1.0f / (1.0f + __expf(-gv));
        int n = nb + mt * 16 + l4 * 4 + rr;
        int sw = (n & 7) << 4;
        int c0 = pair * 32 + l15;
        *(ushort_a*)(Stg + ((n * 256 + c0 * 2) ^ sw)) = f2bf(xo[mt][0][rr] * sg);
        *(ushort_a*)(Stg + ((n * 256 + (c0 + 16) * 2) ^ sw)) = f2bf(xo[mt][1][rr] * sg);
      }
    }
    __syncthreads();
    {
      const unsigned short* wao0 =
          waoB + (size_t)(wave * 48 + l15) * 384 + r * 128 + l4 * 8;
#pragma unroll
      for (int ks = 0; ks < 4; ++ks) {
        int kb = ks * 64 + l4 * 16, sz = (l15 & 7) << 4;
        bf16x8 a0 = *(const bf16x8*)(Stg + ((l15 * 256 + kb) ^ sz));
        bf16x8 a1 = *(const bf16x8*)(Stg + (((16 + l15) * 256 + kb) ^ sz));
        bf16x8 a2 = *(const bf16x8*)(Stg + (((32 + l15) * 256 + kb) ^ sz));
        bf16x8 a3 = *(const bf16x8*)(Stg + (((48 + l15) * 256 + kb) ^ sz));
#pragma unroll
        for (int nt = 0; nt < 3; ++nt) {
          bf16x8 bw = *(const bf16x8*)(wao0 + (size_t)nt * 16 * 384 + ks * 32);
          of[0][nt] = MFMA(a0, bw, of[0][nt]);
          of[1][nt] = MFMA(a1, bw, of[1][nt]);
          of[2][nt] = MFMA(a2, bw, of[2][nt]);
          of[3][nt] = MFMA(a3, bw, of[3][nt]);
        }
      }
    }
  }
#pragma unroll 1
  for (int tg = 0; tg < 6; ++tg) {
    f32x4 ffr[4][2] = {};
    const unsigned short* wfin0 =
        wfB + (size_t)(768 + tg * 256 + wave * 16 + l15) * 384 + l4 * 8;
    const unsigned short* wfin1 = wfin0 + (size_t)128 * 384;
#pragma unroll 2
    for (int ks = 0; ks < 12; ++ks) {
      bf16x8 a0 = ldA(l15, ks), a1 = ldA(16 + l15, ks), a2 = ldA(32 + l15, ks),
             a3 = ldA(48 + l15, ks);
      bf16x8 bw0 = *(const bf16x8*)(wfin0 + ks * 32);
      ffr[0][0] = MFMA(a0, bw0, ffr[0][0]);
      ffr[1][0] = MFMA(a1, bw0, ffr[1][0]);
      ffr[2][0] = MFMA(a2, bw0, ffr[2][0]);
      ffr[3][0] = MFMA(a3, bw0, ffr[3][0]);
      bf16x8 bw1 = *(const bf16x8*)(wfin1 + ks * 32);
      ffr[0][1] = MFMA(a0, bw1, ffr[0][1]);
      ffr[1][1] = MFMA(a1, bw1, ffr[1][1]);
      ffr[2][1] = MFMA(a2, bw1, ffr[2][1]);
      ffr[3][1] = MFMA(a3, bw1, ffr[3][1]);
    }
#pragma unroll
    for (int u = 0; u < 2; ++u) {
      char* fb = smem + 49152 + u * 16384;
#pragma unroll
      for (int mt = 0; mt < 4; ++mt)
#pragma unroll
        for (int rr = 0; rr < 4; ++rr) {
          float v = fmaxf(ffr[mt][u][rr], 0.0f);
          v = ss * v * v + sbi;
          int n = mt * 16 + l4 * 4 + rr;
          int cw = wave * 16 + l15;
          *(ushort_a*)(fb + ((n * 256 + cw * 2) ^ ((n & 7) << 4))) = f2bf(v);
        }
    }
    __syncthreads();
#pragma unroll 1
    for (int u = 0; u < 2; ++u) {
      char* fb = smem + 49152 + u * 16384;
      const unsigned short* wfo2 =
          wfoB + (size_t)(wave * 48 + l15) * 1536 + (tg * 2 + u) * 128 + l4 * 8;
#pragma unroll
      for (int ks = 0; ks < 4; ++ks) {
        int kb = ks * 64 + l4 * 16, sz = (l15 & 7) << 4;
        bf16x8 a0 = *(const bf16x8*)(fb + ((l15 * 256 + kb) ^ sz));
        bf16x8 a1 = *(const bf16x8*)(fb + (((16 + l15) * 256 + kb) ^ sz));
        bf16x8 a2 = *(const bf16x8*)(fb + (((32 + l15) * 256 + kb) ^ sz));
        bf16x8 a3 = *(const bf16x8*)(fb + (((48 + l15) * 256 + kb) ^ sz));
#pragma unroll
        for (int nt = 0; nt < 3; ++nt) {
          bf16x8 bw = *(const bf16x8*)(wfo2 + (size_t)nt * 16 * 1536 + ks * 32);
          of[0][nt] = MFMA(a0, bw, of[0][nt]);
          of[1][nt] = MFMA(a1, bw, of[1][nt]);
          of[2][nt] = MFMA(a2, bw, of[2][nt]);
          of[3][nt] = MFMA(a3, bw, of[3][nt]);
        }
      }
    }
    __syncthreads();
  }
  float* ob = out + (size_t)b * 1572864 + h0 * 64 + w0;
#pragma unroll
  for (int nt = 0; nt < 3; ++nt) {
    int col = wave * 48 + nt * 16 + l15;
    float* oc = ob + (size_t)col * 4096;
#pragma unroll
    for (int mt = 0; mt < 4; ++mt) {
      int n0 = mt * 16 + l4 * 4;
      *(f32x4*)(oc + (n0 >> 3) * 64 + (n0 & 7)) = of[mt][nt];
    }
  }
}

extern "C" void kernel_launch(void* const* d_in, const int* in_sizes, int n_in,
                              void* d_out, int out_size, void* d_ws, size_t ws_size,
                              hipStream_t stream) {
  const float* x = (const float*)d_in[0];
  const float* wf = (const float*)d_in[1];
  const float* wg = (const float*)d_in[2];
  const float* bg = (const float*)d_in[3];
  const float* wao = (const float*)d_in[4];
  const float* wfo = (const float*)d_in[5];
  const float* srs = (const float*)d_in[6];
  const float* srb = (const float*)d_in[7];
  unsigned short* ws = (unsigned short*)d_ws;

  prep_weights<<<6528, 256, 0, stream>>>(wf, wg, wao, wfo, ws);
  if (ws_size >= WS_NEED) {
    k0_gather<<<1024, 256, 0, stream>>>(x, ws + OFF_XG);
    k1_gemm<<<512 * 19, 512, 0, stream>>>(ws, srs, srb);
    k2_attn<<<1024, 256, 0, stream>>>(ws, bg);
    k3_gemm<<<512 * 3, 512, 0, stream>>>(ws, (float*)d_out);
  } else {
    fused_fallback<<<1024, 512, 0, stream>>>(x, bg, srs, srb, ws, (float*)d_out);
  }
}